// Round 1
// baseline (6305.285 us; speedup 1.0000x reference)
//
#include <hip/hip_runtime.h>

#define NN 200000
#define NE 4000000
#define FIN 64
#define DIM 20
#define NGR 512
#define NCL 2
#define BN_EPS 1e-5f

// ---------------- degree ----------------
__global__ __launch_bounds__(256) void deg_kernel(const int* __restrict__ dst, int* __restrict__ cnt) {
    int e = blockIdx.x * 256 + threadIdx.x;
    if (e < NE) atomicAdd(&cnt[dst[e]], 1);
}

__global__ __launch_bounds__(256) void dinv_kernel(const int* __restrict__ cnt, float* __restrict__ dinv) {
    int n = blockIdx.x * 256 + threadIdx.x;
    if (n < NN) dinv[n] = rsqrtf(1.0f + (float)cnt[n]);
}

// ---------------- layer0 linear: x[N,64] @ W0[64,20] -> out[N,20] ----------------
__global__ __launch_bounds__(256) void lin0_kernel(const float* __restrict__ x, const float* __restrict__ W,
                                                   float* __restrict__ out) {
    __shared__ float sW[FIN * DIM];   // 1280
    __shared__ float sX[64 * 65];     // 64 nodes x 64 feats, pad 65
    int tid = threadIdx.x;
    for (int i = tid; i < FIN * DIM; i += 256) sW[i] = W[i];
    int n0 = blockIdx.x * 64;
    #pragma unroll
    for (int k = 0; k < 16; ++k) {
        int idx = tid + k * 256;
        int row = idx >> 6, col = idx & 63;
        sX[row * 65 + col] = x[(n0 + row) * FIN + col];
    }
    __syncthreads();
    int nl = tid & 63, wq = tid >> 6;   // node_local, output-col quarter
    float acc[5] = {0.f, 0.f, 0.f, 0.f, 0.f};
    for (int f = 0; f < FIN; ++f) {
        float xv = sX[nl * 65 + f];
        #pragma unroll
        for (int k = 0; k < 5; ++k) acc[k] += xv * sW[f * DIM + wq + 4 * k];
    }
    int n = n0 + nl;
    #pragma unroll
    for (int k = 0; k < 5; ++k) out[n * DIM + wq + 4 * k] = acc[k];
}

// ---------------- init agg with self-loop + bias ----------------
__global__ __launch_bounds__(256) void init_agg_kernel(const float* __restrict__ xl, const float* __restrict__ dinv,
                                                       const float* __restrict__ b, float* __restrict__ agg) {
    int gid = blockIdx.x * 256 + threadIdx.x;
    if (gid >= NN * DIM) return;
    int n = gid / DIM, d = gid - n * DIM;
    float di = dinv[n];
    agg[gid] = xl[gid] * di * di + b[d];
}

// ---------------- edge scatter: agg[dst] += xl[src] * dinv[src]*dinv[dst] ----------------
__global__ __launch_bounds__(256) void edge_kernel(const int* __restrict__ src, const int* __restrict__ dst,
                                                   const float* __restrict__ dinv, const float* __restrict__ xl,
                                                   float* __restrict__ agg) {
    int tid = threadIdx.x;
    int e = blockIdx.x * 64 + (tid >> 2);
    if (e >= NE) return;
    int s = src[e], t = dst[e];
    float norm = dinv[s] * dinv[t];
    int q = tid & 3;                       // 4 threads/edge, 5 feats each
    const float* xs = xl + s * DIM + q * 5;
    float* at = agg + t * DIM + q * 5;
    #pragma unroll
    for (int j = 0; j < 5; ++j) atomicAdd(&at[j], xs[j] * norm);
}

// ---------------- BN stats: per-feature sum & sumsq ----------------
__global__ __launch_bounds__(256) void stats_kernel(const float* __restrict__ a, float* __restrict__ stats) {
    __shared__ float ssum[DIM], ssq[DIM];
    int tid = threadIdx.x;
    if (tid < DIM) { ssum[tid] = 0.f; ssq[tid] = 0.f; }
    __syncthreads();
    int gid = blockIdx.x * 256 + tid;
    const int stride = 2500 * 256;          // % DIM == 0 -> d constant per thread
    int d = gid % DIM;
    float s = 0.f, q = 0.f;
    for (int i = gid; i < NN * DIM; i += stride) { float v = a[i]; s += v; q += v * v; }
    atomicAdd(&ssum[d], s);
    atomicAdd(&ssq[d], q);
    __syncthreads();
    if (tid < DIM) { atomicAdd(&stats[tid], ssum[tid]); atomicAdd(&stats[DIM + tid], ssq[tid]); }
}

__global__ void bn_param_kernel(const float* __restrict__ stats, const float* __restrict__ g,
                                const float* __restrict__ beta, float* __restrict__ ss) {
    int d = threadIdx.x;
    if (d < DIM) {
        float mean = stats[d] * (1.0f / NN);
        float var = stats[DIM + d] * (1.0f / NN) - mean * mean;
        float sc = g[d] * rsqrtf(var + BN_EPS);
        ss[d] = sc;
        ss[DIM + d] = beta[d] - mean * sc;
    }
}

// ---------------- next linear fused with relu(bn(.)) on input ----------------
__global__ __launch_bounds__(256) void lin_next_kernel(const float* __restrict__ a, const float* __restrict__ ss,
                                                       const float* __restrict__ W, float* __restrict__ out) {
    __shared__ float sW[DIM * DIM];   // 400
    __shared__ float sH[64 * 21];     // 64 nodes x 20, pad 21
    __shared__ float sS[2 * DIM];
    int tid = threadIdx.x;
    for (int i = tid; i < DIM * DIM; i += 256) sW[i] = W[i];
    if (tid < 2 * DIM) sS[tid] = ss[tid];
    __syncthreads();
    int n0 = blockIdx.x * 64;
    #pragma unroll
    for (int k = 0; k < 5; ++k) {
        int idx = tid + k * 256;      // 0..1279
        int row = idx / DIM, col = idx - row * DIM;
        float v = a[(n0 + row) * DIM + col];
        sH[row * 21 + col] = fmaxf(v * sS[col] + sS[DIM + col], 0.0f);
    }
    __syncthreads();
    int nl = tid & 63, wq = tid >> 6;
    float acc[5] = {0.f, 0.f, 0.f, 0.f, 0.f};
    for (int f = 0; f < DIM; ++f) {
        float h = sH[nl * 21 + f];
        #pragma unroll
        for (int k = 0; k < 5; ++k) acc[k] += h * sW[f * DIM + wq + 4 * k];
    }
    int n = n0 + nl;
    #pragma unroll
    for (int k = 0; k < 5; ++k) out[n * DIM + wq + 4 * k] = acc[k];
}

// ---------------- final: relu(bn) -> emb out + segment_max via atomicMax ----------------
__global__ __launch_bounds__(256) void final_kernel(const float* __restrict__ a, const float* __restrict__ ss,
                                                    const int* __restrict__ batch, float* __restrict__ emb,
                                                    unsigned int* __restrict__ ge) {
    int gid = blockIdx.x * 256 + threadIdx.x;
    if (gid >= NN * DIM) return;
    int n = gid / DIM, d = gid - n * DIM;
    float v = fmaxf(a[gid] * ss[d] + ss[DIM + d], 0.0f);
    emb[gid] = v;
    atomicMax(&ge[batch[n] * DIM + d], __float_as_uint(v));  // v >= 0 so uint-order == float-order
}

// ---------------- fc head ----------------
__global__ __launch_bounds__(256) void fc_kernel(const float* __restrict__ ge, const float* __restrict__ fcW,
                                                 const float* __restrict__ fcb, float* __restrict__ out) {
    int gid = blockIdx.x * 256 + threadIdx.x;
    if (gid >= NGR * NCL) return;
    int g = gid >> 1, c = gid & 1;
    float acc = fcb[c];
    #pragma unroll
    for (int d = 0; d < DIM; ++d) acc += ge[g * DIM + d] * fcW[d * NCL + c];
    out[gid] = acc;
}

extern "C" void kernel_launch(void* const* d_in, const int* in_sizes, int n_in,
                              void* d_out, int out_size, void* d_ws, size_t ws_size,
                              hipStream_t stream) {
    const float* x    = (const float*)d_in[0];
    const int*   ei   = (const int*)d_in[1];
    const int*   src  = ei;
    const int*   dst  = ei + NE;
    const int*   batch = (const int*)d_in[2];
    const float* W0 = (const float*)d_in[3];  const float* b0 = (const float*)d_in[4];
    const float* g0 = (const float*)d_in[5];  const float* be0 = (const float*)d_in[6];
    const float* W1 = (const float*)d_in[7];  const float* b1 = (const float*)d_in[8];
    const float* g1 = (const float*)d_in[9];  const float* be1 = (const float*)d_in[10];
    const float* W2 = (const float*)d_in[11]; const float* b2 = (const float*)d_in[12];
    const float* g2 = (const float*)d_in[13]; const float* be2 = (const float*)d_in[14];
    const float* fcW = (const float*)d_in[15]; const float* fcb = (const float*)d_in[16];

    float* ws   = (float*)d_ws;
    float* dinv = ws;                       // N
    int*   cnt  = (int*)(ws + NN);          // N ints
    float* bufA = ws + 2 * NN;              // N*DIM
    float* bufB = bufA + NN * DIM;          // N*DIM
    float* stats = bufB + NN * DIM;         // 3 * 64
    float* ss    = stats + 192;             // 3 * 40

    float* emb    = (float*)d_out;          // N*DIM
    float* ge     = emb + NN * DIM;         // NGR*DIM
    float* logits = ge + NGR * DIM;         // NGR*NCL

    hipMemsetAsync(cnt, 0, NN * sizeof(int), stream);
    hipMemsetAsync(stats, 0, 192 * sizeof(float), stream);
    hipMemsetAsync(ge, 0, NGR * DIM * sizeof(float), stream);

    deg_kernel<<<(NE + 255) / 256, 256, 0, stream>>>(dst, cnt);
    dinv_kernel<<<(NN + 255) / 256, 256, 0, stream>>>(cnt, dinv);

    lin0_kernel<<<NN / 64, 256, 0, stream>>>(x, W0, bufA);

    const int GE_BLKS = (NN * DIM) / 256;   // 15625 exact
    const int EDGE_BLKS = NE / 64;          // 62500 exact

    // layer 0
    init_agg_kernel<<<GE_BLKS, 256, 0, stream>>>(bufA, dinv, b0, bufB);
    edge_kernel<<<EDGE_BLKS, 256, 0, stream>>>(src, dst, dinv, bufA, bufB);
    stats_kernel<<<2500, 256, 0, stream>>>(bufB, stats);
    bn_param_kernel<<<1, 32, 0, stream>>>(stats, g0, be0, ss);
    lin_next_kernel<<<NN / 64, 256, 0, stream>>>(bufB, ss, W1, bufA);

    // layer 1
    init_agg_kernel<<<GE_BLKS, 256, 0, stream>>>(bufA, dinv, b1, bufB);
    edge_kernel<<<EDGE_BLKS, 256, 0, stream>>>(src, dst, dinv, bufA, bufB);
    stats_kernel<<<2500, 256, 0, stream>>>(bufB, stats + 64);
    bn_param_kernel<<<1, 32, 0, stream>>>(stats + 64, g1, be1, ss + 40);
    lin_next_kernel<<<NN / 64, 256, 0, stream>>>(bufB, ss + 40, W2, bufA);

    // layer 2
    init_agg_kernel<<<GE_BLKS, 256, 0, stream>>>(bufA, dinv, b2, bufB);
    edge_kernel<<<EDGE_BLKS, 256, 0, stream>>>(src, dst, dinv, bufA, bufB);
    stats_kernel<<<2500, 256, 0, stream>>>(bufB, stats + 128);
    bn_param_kernel<<<1, 32, 0, stream>>>(stats + 128, g2, be2, ss + 80);

    final_kernel<<<GE_BLKS, 256, 0, stream>>>(bufB, ss + 80, batch, emb, (unsigned int*)ge);
    fc_kernel<<<(NGR * NCL + 255) / 256, 256, 0, stream>>>(ge, fcW, fcb, logits);
}

// Round 2
// 1635.406 us; speedup vs baseline: 3.8555x; 3.8555x over previous
//
#include <hip/hip_runtime.h>

#define NN 200000
#define NE 4000000
#define FIN 64
#define DIM 20
#define NGR 512
#define NCL 2
#define BN_EPS 1e-5f

// ---------------- degree ----------------
__global__ __launch_bounds__(256) void deg_kernel(const int* __restrict__ dst, int* __restrict__ cnt) {
    int e = blockIdx.x * 256 + threadIdx.x;
    if (e < NE) atomicAdd(&cnt[dst[e]], 1);
}

__global__ __launch_bounds__(256) void dinv_kernel(const int* __restrict__ cnt, float* __restrict__ dinv) {
    int n = blockIdx.x * 256 + threadIdx.x;
    if (n < NN) dinv[n] = rsqrtf(1.0f + (float)cnt[n]);
}

// ---------------- exclusive scan of cnt -> rowstart (single block) ----------------
__global__ __launch_bounds__(1024) void scan_kernel(const int* __restrict__ cnt, int* __restrict__ rowstart) {
    __shared__ int lsum[1024];
    int t = threadIdx.x;
    const int CH = (NN + 1023) / 1024;   // 196
    int beg = t * CH, end = min(beg + CH, NN);
    int s = 0;
    for (int i = beg; i < end; ++i) s += cnt[i];
    lsum[t] = s;
    __syncthreads();
    for (int off = 1; off < 1024; off <<= 1) {   // Hillis-Steele inclusive scan
        int v = (t >= off) ? lsum[t - off] : 0;
        __syncthreads();
        lsum[t] += v;
        __syncthreads();
    }
    int run = (t == 0) ? 0 : lsum[t - 1];
    for (int i = beg; i < end; ++i) { rowstart[i] = run; run += cnt[i]; }
    if (t == 1023) rowstart[NN] = run;   // == NE
}

// ---------------- CSR placement: col sorted by dst ----------------
__global__ __launch_bounds__(256) void place_kernel(const int* __restrict__ src, const int* __restrict__ dst,
                                                    const int* __restrict__ rowstart, int* __restrict__ cursor,
                                                    int* __restrict__ col) {
    int e = blockIdx.x * 256 + threadIdx.x;
    if (e >= NE) return;
    int t = dst[e];
    int pos = rowstart[t] + atomicAdd(&cursor[t], 1);
    col[pos] = src[e];
}

// ---------------- layer0 linear: x[N,64] @ W0[64,20] -> out[N,20] ----------------
__global__ __launch_bounds__(256) void lin0_kernel(const float* __restrict__ x, const float* __restrict__ W,
                                                   float* __restrict__ out) {
    __shared__ float sW[FIN * DIM];
    __shared__ float sX[64 * 65];
    int tid = threadIdx.x;
    for (int i = tid; i < FIN * DIM; i += 256) sW[i] = W[i];
    int n0 = blockIdx.x * 64;
    #pragma unroll
    for (int k = 0; k < 16; ++k) {
        int idx = tid + k * 256;
        int row = idx >> 6, colf = idx & 63;
        sX[row * 65 + colf] = x[(n0 + row) * FIN + colf];
    }
    __syncthreads();
    int nl = tid & 63, wq = tid >> 6;
    float acc[5] = {0.f, 0.f, 0.f, 0.f, 0.f};
    for (int f = 0; f < FIN; ++f) {
        float xv = sX[nl * 65 + f];
        #pragma unroll
        for (int k = 0; k < 5; ++k) acc[k] += xv * sW[f * DIM + wq + 4 * k];
    }
    int n = n0 + nl;
    #pragma unroll
    for (int k = 0; k < 5; ++k) out[n * DIM + wq + 4 * k] = acc[k];
}

// ---------------- CSR gather-aggregate + self-loop + bias, fused BN stats ----------------
__global__ __launch_bounds__(256) void gather_kernel(const float* __restrict__ xl, const int* __restrict__ col,
                                                     const int* __restrict__ rowstart, const float* __restrict__ dinv,
                                                     const float* __restrict__ b, float* __restrict__ agg,
                                                     float* __restrict__ stats) {
    __shared__ float ls[2 * DIM];
    int tid = threadIdx.x;
    if (tid < 2 * DIM) ls[tid] = 0.f;
    __syncthreads();
    int n = blockIdx.x * 256 + tid;
    float acc[DIM];
    bool valid = (n < NN);
    if (valid) {
        float di = dinv[n];
        float sl = di * di;
        const float4* xr = (const float4*)(xl + (size_t)n * DIM);
        #pragma unroll
        for (int c = 0; c < 5; ++c) {
            float4 v = xr[c];
            acc[4*c+0] = v.x * sl + b[4*c+0];
            acc[4*c+1] = v.y * sl + b[4*c+1];
            acc[4*c+2] = v.z * sl + b[4*c+2];
            acc[4*c+3] = v.w * sl + b[4*c+3];
        }
        int beg = rowstart[n], end = rowstart[n + 1];
        for (int e = beg; e < end; ++e) {
            int s = col[e];
            float norm = dinv[s] * di;
            const float4* xs = (const float4*)(xl + (size_t)s * DIM);
            #pragma unroll
            for (int c = 0; c < 5; ++c) {
                float4 v = xs[c];
                acc[4*c+0] += v.x * norm;
                acc[4*c+1] += v.y * norm;
                acc[4*c+2] += v.z * norm;
                acc[4*c+3] += v.w * norm;
            }
        }
        float4* ar = (float4*)(agg + (size_t)n * DIM);
        #pragma unroll
        for (int c = 0; c < 5; ++c)
            ar[c] = make_float4(acc[4*c+0], acc[4*c+1], acc[4*c+2], acc[4*c+3]);
        #pragma unroll
        for (int j = 0; j < DIM; ++j) {
            atomicAdd(&ls[j], acc[j]);
            atomicAdd(&ls[DIM + j], acc[j] * acc[j]);
        }
    }
    __syncthreads();
    if (tid < 2 * DIM) atomicAdd(&stats[tid], ls[tid]);
}

__global__ void bn_param_kernel(const float* __restrict__ stats, const float* __restrict__ g,
                                const float* __restrict__ beta, float* __restrict__ ss) {
    int d = threadIdx.x;
    if (d < DIM) {
        float mean = stats[d] * (1.0f / NN);
        float var = stats[DIM + d] * (1.0f / NN) - mean * mean;
        float sc = g[d] * rsqrtf(var + BN_EPS);
        ss[d] = sc;
        ss[DIM + d] = beta[d] - mean * sc;
    }
}

// ---------------- next linear fused with relu(bn(.)) on input ----------------
__global__ __launch_bounds__(256) void lin_next_kernel(const float* __restrict__ a, const float* __restrict__ ss,
                                                       const float* __restrict__ W, float* __restrict__ out) {
    __shared__ float sW[DIM * DIM];
    __shared__ float sH[64 * 21];
    __shared__ float sS[2 * DIM];
    int tid = threadIdx.x;
    for (int i = tid; i < DIM * DIM; i += 256) sW[i] = W[i];
    if (tid < 2 * DIM) sS[tid] = ss[tid];
    __syncthreads();
    int n0 = blockIdx.x * 64;
    #pragma unroll
    for (int k = 0; k < 5; ++k) {
        int idx = tid + k * 256;
        int row = idx / DIM, colf = idx - row * DIM;
        float v = a[(n0 + row) * DIM + colf];
        sH[row * 21 + colf] = fmaxf(v * sS[colf] + sS[DIM + colf], 0.0f);
    }
    __syncthreads();
    int nl = tid & 63, wq = tid >> 6;
    float acc[5] = {0.f, 0.f, 0.f, 0.f, 0.f};
    for (int f = 0; f < DIM; ++f) {
        float h = sH[nl * 21 + f];
        #pragma unroll
        for (int k = 0; k < 5; ++k) acc[k] += h * sW[f * DIM + wq + 4 * k];
    }
    int n = n0 + nl;
    #pragma unroll
    for (int k = 0; k < 5; ++k) out[n * DIM + wq + 4 * k] = acc[k];
}

// ---------------- final: relu(bn) -> emb out + segment_max via atomicMax ----------------
__global__ __launch_bounds__(256) void final_kernel(const float* __restrict__ a, const float* __restrict__ ss,
                                                    const int* __restrict__ batch, float* __restrict__ emb,
                                                    unsigned int* __restrict__ ge) {
    int gid = blockIdx.x * 256 + threadIdx.x;
    if (gid >= NN * DIM) return;
    int n = gid / DIM, d = gid - n * DIM;
    float v = fmaxf(a[gid] * ss[d] + ss[DIM + d], 0.0f);
    emb[gid] = v;
    atomicMax(&ge[batch[n] * DIM + d], __float_as_uint(v));  // v >= 0: uint order == float order
}

// ---------------- fc head ----------------
__global__ __launch_bounds__(256) void fc_kernel(const float* __restrict__ ge, const float* __restrict__ fcW,
                                                 const float* __restrict__ fcb, float* __restrict__ out) {
    int gid = blockIdx.x * 256 + threadIdx.x;
    if (gid >= NGR * NCL) return;
    int g = gid >> 1, c = gid & 1;
    float acc = fcb[c];
    #pragma unroll
    for (int d = 0; d < DIM; ++d) acc += ge[g * DIM + d] * fcW[d * NCL + c];
    out[gid] = acc;
}

extern "C" void kernel_launch(void* const* d_in, const int* in_sizes, int n_in,
                              void* d_out, int out_size, void* d_ws, size_t ws_size,
                              hipStream_t stream) {
    const float* x    = (const float*)d_in[0];
    const int*   ei   = (const int*)d_in[1];
    const int*   src  = ei;
    const int*   dst  = ei + NE;
    const int*   batch = (const int*)d_in[2];
    const float* W0 = (const float*)d_in[3];  const float* b0 = (const float*)d_in[4];
    const float* g0 = (const float*)d_in[5];  const float* be0 = (const float*)d_in[6];
    const float* W1 = (const float*)d_in[7];  const float* b1 = (const float*)d_in[8];
    const float* g1 = (const float*)d_in[9];  const float* be1 = (const float*)d_in[10];
    const float* W2 = (const float*)d_in[11]; const float* b2 = (const float*)d_in[12];
    const float* g2 = (const float*)d_in[13]; const float* be2 = (const float*)d_in[14];
    const float* fcW = (const float*)d_in[15]; const float* fcb = (const float*)d_in[16];

    float* ws      = (float*)d_ws;
    float* dinv    = ws;                         // NN floats
    int*   cnt     = (int*)(ws + NN);            // NN ints (reused as cursor)
    int*   rowstart= (int*)(ws + 2 * NN);        // NN+1 ints
    float* bufA    = ws + 3 * NN + 4;            // NN*DIM, 16B aligned
    float* bufB    = bufA + NN * DIM;            // NN*DIM
    int*   col     = (int*)(bufB + NN * DIM);    // NE ints
    float* stats   = (float*)(col + NE);         // 3 * 64
    float* ss      = stats + 192;                // 3 * 40

    float* emb    = (float*)d_out;               // NN*DIM
    float* ge     = emb + NN * DIM;              // NGR*DIM
    float* logits = ge + NGR * DIM;              // NGR*NCL

    const int GE_BLKS  = (NN * DIM) / 256;       // 15625
    const int E_BLKS   = NE / 256;               // 15625
    const int N_BLKS   = (NN + 255) / 256;       // 782

    hipMemsetAsync(cnt, 0, NN * sizeof(int), stream);
    hipMemsetAsync(stats, 0, 192 * sizeof(float), stream);
    hipMemsetAsync(ge, 0, NGR * DIM * sizeof(float), stream);

    // ---- CSR build (once; shared by all 3 layers) ----
    deg_kernel<<<E_BLKS, 256, 0, stream>>>(dst, cnt);
    dinv_kernel<<<N_BLKS, 256, 0, stream>>>(cnt, dinv);
    scan_kernel<<<1, 1024, 0, stream>>>(cnt, rowstart);
    hipMemsetAsync(cnt, 0, NN * sizeof(int), stream);   // cnt -> cursor
    place_kernel<<<E_BLKS, 256, 0, stream>>>(src, dst, rowstart, cnt, col);

    lin0_kernel<<<NN / 64, 256, 0, stream>>>(x, W0, bufA);

    // layer 0
    gather_kernel<<<N_BLKS, 256, 0, stream>>>(bufA, col, rowstart, dinv, b0, bufB, stats);
    bn_param_kernel<<<1, 32, 0, stream>>>(stats, g0, be0, ss);
    lin_next_kernel<<<NN / 64, 256, 0, stream>>>(bufB, ss, W1, bufA);

    // layer 1
    gather_kernel<<<N_BLKS, 256, 0, stream>>>(bufA, col, rowstart, dinv, b1, bufB, stats + 64);
    bn_param_kernel<<<1, 32, 0, stream>>>(stats + 64, g1, be1, ss + 40);
    lin_next_kernel<<<NN / 64, 256, 0, stream>>>(bufB, ss + 40, W2, bufA);

    // layer 2
    gather_kernel<<<N_BLKS, 256, 0, stream>>>(bufA, col, rowstart, dinv, b2, bufB, stats + 128);
    bn_param_kernel<<<1, 32, 0, stream>>>(stats + 128, g2, be2, ss + 80);

    final_kernel<<<GE_BLKS, 256, 0, stream>>>(bufB, ss + 80, batch, emb, (unsigned int*)ge);
    fc_kernel<<<(NGR * NCL + 255) / 256, 256, 0, stream>>>(ge, fcW, fcb, logits);
}

// Round 3
// 947.538 us; speedup vs baseline: 6.6544x; 1.7260x over previous
//
#include <hip/hip_runtime.h>

#define NN 200000
#define NE 4000000
#define FIN 64
#define DIM 20
#define NGR 512
#define NCL 2
#define BN_EPS 1e-5f
#define NB_SCAN 782   // ceil(NN/256)

// ---------------- degree ----------------
__global__ __launch_bounds__(256) void deg_kernel(const int* __restrict__ dst, int* __restrict__ cnt) {
    int e = blockIdx.x * 256 + threadIdx.x;
    if (e < NE) atomicAdd(&cnt[dst[e]], 1);
}

__global__ __launch_bounds__(256) void dinv_kernel(const int* __restrict__ cnt, float* __restrict__ dinv) {
    int n = blockIdx.x * 256 + threadIdx.x;
    if (n < NN) dinv[n] = rsqrtf(1.0f + (float)cnt[n]);
}

// ---------------- 3-phase exclusive scan of cnt -> rowstart ----------------
__global__ __launch_bounds__(256) void scan1_kernel(const int* __restrict__ cnt, int* __restrict__ bsum) {
    int i = blockIdx.x * 256 + threadIdx.x;
    int v = (i < NN) ? cnt[i] : 0;
    #pragma unroll
    for (int off = 32; off > 0; off >>= 1) v += __shfl_down(v, off, 64);
    __shared__ int ws[4];
    if ((threadIdx.x & 63) == 0) ws[threadIdx.x >> 6] = v;
    __syncthreads();
    if (threadIdx.x == 0) bsum[blockIdx.x] = ws[0] + ws[1] + ws[2] + ws[3];
}

__global__ __launch_bounds__(1024) void scan2_kernel(int* __restrict__ bsum) {
    __shared__ int tmp[1024];
    int t = threadIdx.x;
    int v = (t < NB_SCAN) ? bsum[t] : 0;
    tmp[t] = v;
    __syncthreads();
    for (int off = 1; off < 1024; off <<= 1) {
        int u = (t >= off) ? tmp[t - off] : 0;
        __syncthreads();
        tmp[t] += u;
        __syncthreads();
    }
    if (t < NB_SCAN) bsum[t] = tmp[t] - v;   // exclusive
}

__global__ __launch_bounds__(256) void scan3_kernel(const int* __restrict__ cnt, const int* __restrict__ bsum,
                                                    int* __restrict__ rowstart) {
    __shared__ int tmp[256];
    int t = threadIdx.x;
    int i = blockIdx.x * 256 + t;
    int v = (i < NN) ? cnt[i] : 0;
    tmp[t] = v;
    __syncthreads();
    for (int off = 1; off < 256; off <<= 1) {
        int u = (t >= off) ? tmp[t - off] : 0;
        __syncthreads();
        tmp[t] += u;
        __syncthreads();
    }
    int incl = tmp[t];
    int base = bsum[blockIdx.x];
    if (i < NN) rowstart[i] = base + incl - v;
    if (i == NN - 1) rowstart[NN] = base + incl;
}

// ---------------- CSR placement ----------------
__global__ __launch_bounds__(256) void place_kernel(const int* __restrict__ src, const int* __restrict__ dst,
                                                    const int* __restrict__ rowstart, int* __restrict__ cursor,
                                                    int* __restrict__ col) {
    int e = blockIdx.x * 256 + threadIdx.x;
    if (e >= NE) return;
    int t = dst[e];
    int pos = rowstart[t] + atomicAdd(&cursor[t], 1);
    col[pos] = src[e];
}

// ---------------- layer0 linear: x[N,64] @ W0[64,20] ----------------
__global__ __launch_bounds__(256) void lin0_kernel(const float* __restrict__ x, const float* __restrict__ W,
                                                   float* __restrict__ out) {
    __shared__ float sW[FIN * DIM];
    __shared__ float sX[64 * 65];
    int tid = threadIdx.x;
    for (int i = tid; i < FIN * DIM; i += 256) sW[i] = W[i];
    int n0 = blockIdx.x * 64;
    #pragma unroll
    for (int k = 0; k < 16; ++k) {
        int idx = tid + k * 256;
        int row = idx >> 6, colf = idx & 63;
        sX[row * 65 + colf] = x[(n0 + row) * FIN + colf];
    }
    __syncthreads();
    int nl = tid & 63, wq = tid >> 6;
    float acc[5] = {0.f, 0.f, 0.f, 0.f, 0.f};
    for (int f = 0; f < FIN; ++f) {
        float xv = sX[nl * 65 + f];
        #pragma unroll
        for (int k = 0; k < 5; ++k) acc[k] += xv * sW[f * DIM + wq + 4 * k];
    }
    int n = n0 + nl;
    #pragma unroll
    for (int k = 0; k < 5; ++k) out[n * DIM + wq + 4 * k] = acc[k];
}

// ---------------- CSR gather: 2 lanes per node, fused BN stats ----------------
__global__ __launch_bounds__(256) void gather_kernel(const float* __restrict__ xl, const int* __restrict__ col,
                                                     const int* __restrict__ rowstart, const float* __restrict__ dinv,
                                                     const float* __restrict__ b, float* __restrict__ agg,
                                                     float* __restrict__ stats) {
    __shared__ float ls[2 * DIM];
    int tid = threadIdx.x;
    if (tid < 2 * DIM) ls[tid] = 0.f;
    __syncthreads();
    int n = blockIdx.x * 128 + (tid >> 1);
    int half = tid & 1;
    float acc[DIM];
    if (n < NN) {
        float di = dinv[n];
        if (half == 0) {
            float sl = di * di;
            const float4* xr = (const float4*)(xl + (size_t)n * DIM);
            #pragma unroll
            for (int c = 0; c < 5; ++c) {
                float4 v = xr[c];
                acc[4*c+0] = v.x * sl + b[4*c+0];
                acc[4*c+1] = v.y * sl + b[4*c+1];
                acc[4*c+2] = v.z * sl + b[4*c+2];
                acc[4*c+3] = v.w * sl + b[4*c+3];
            }
        } else {
            #pragma unroll
            for (int j = 0; j < DIM; ++j) acc[j] = 0.f;
        }
        int beg = rowstart[n], end = rowstart[n + 1];
        for (int e = beg + half; e < end; e += 2) {
            int s = col[e];
            float norm = dinv[s] * di;
            const float4* xs = (const float4*)(xl + (size_t)s * DIM);
            #pragma unroll
            for (int c = 0; c < 5; ++c) {
                float4 v = xs[c];
                acc[4*c+0] += v.x * norm;
                acc[4*c+1] += v.y * norm;
                acc[4*c+2] += v.z * norm;
                acc[4*c+3] += v.w * norm;
            }
        }
        #pragma unroll
        for (int j = 0; j < DIM; ++j) acc[j] += __shfl_xor(acc[j], 1, 64);
        // pair now holds full row; split the write
        float4* ar = (float4*)(agg + (size_t)n * DIM);
        if (half == 0) {
            #pragma unroll
            for (int c = 0; c < 3; ++c) ar[c] = make_float4(acc[4*c+0], acc[4*c+1], acc[4*c+2], acc[4*c+3]);
        } else {
            #pragma unroll
            for (int c = 3; c < 5; ++c) ar[c] = make_float4(acc[4*c+0], acc[4*c+1], acc[4*c+2], acc[4*c+3]);
        }
        // stats: 10 feats per lane, rotated start to spread LDS banks
        int pr = tid >> 1;
        #pragma unroll
        for (int jo = 0; jo < 10; ++jo) {
            int j = ((jo + pr) % 10) + 10 * half;
            atomicAdd(&ls[j], acc[j]);
            atomicAdd(&ls[DIM + j], acc[j] * acc[j]);
        }
    }
    __syncthreads();
    if (tid < 2 * DIM) atomicAdd(&stats[tid], ls[tid]);
}

__global__ void bn_param_kernel(const float* __restrict__ stats, const float* __restrict__ g,
                                const float* __restrict__ beta, float* __restrict__ ss) {
    int d = threadIdx.x;
    if (d < DIM) {
        float mean = stats[d] * (1.0f / NN);
        float var = stats[DIM + d] * (1.0f / NN) - mean * mean;
        float sc = g[d] * rsqrtf(var + BN_EPS);
        ss[d] = sc;
        ss[DIM + d] = beta[d] - mean * sc;
    }
}

// ---------------- next linear fused with relu(bn(.)) ----------------
__global__ __launch_bounds__(256) void lin_next_kernel(const float* __restrict__ a, const float* __restrict__ ss,
                                                       const float* __restrict__ W, float* __restrict__ out) {
    __shared__ float sW[DIM * DIM];
    __shared__ float sH[64 * 21];
    __shared__ float sS[2 * DIM];
    int tid = threadIdx.x;
    for (int i = tid; i < DIM * DIM; i += 256) sW[i] = W[i];
    if (tid < 2 * DIM) sS[tid] = ss[tid];
    __syncthreads();
    int n0 = blockIdx.x * 64;
    #pragma unroll
    for (int k = 0; k < 5; ++k) {
        int idx = tid + k * 256;
        int row = idx / DIM, colf = idx - row * DIM;
        float v = a[(n0 + row) * DIM + colf];
        sH[row * 21 + colf] = fmaxf(v * sS[colf] + sS[DIM + colf], 0.0f);
    }
    __syncthreads();
    int nl = tid & 63, wq = tid >> 6;
    float acc[5] = {0.f, 0.f, 0.f, 0.f, 0.f};
    for (int f = 0; f < DIM; ++f) {
        float h = sH[nl * 21 + f];
        #pragma unroll
        for (int k = 0; k < 5; ++k) acc[k] += h * sW[f * DIM + wq + 4 * k];
    }
    int n = n0 + nl;
    #pragma unroll
    for (int k = 0; k < 5; ++k) out[n * DIM + wq + 4 * k] = acc[k];
}

// ---------------- final: relu(bn) -> emb + segment_max (LDS pre-reduce; batch sorted) ----------------
__global__ __launch_bounds__(256) void final_kernel(const float* __restrict__ a, const float* __restrict__ ss,
                                                    const int* __restrict__ batch, float* __restrict__ emb,
                                                    unsigned int* __restrict__ ge) {
    __shared__ unsigned int lmax[8 * DIM];
    __shared__ float sS[2 * DIM];
    __shared__ int sg[2];
    int tid = threadIdx.x;
    if (tid < 2 * DIM) sS[tid] = ss[tid];
    int n0 = blockIdx.x * 256;
    if (tid == 0) {
        int nlast = min(n0 + 255, NN - 1);
        sg[0] = batch[n0];
        sg[1] = batch[nlast] - batch[n0] + 1;
    }
    for (int i = tid; i < 8 * DIM; i += 256) lmax[i] = 0u;
    __syncthreads();
    int gmin = sg[0], gspan = sg[1];
    bool uselds = (gspan <= 8);
    int n = n0 + tid;
    if (n < NN) {
        int g = batch[n];
        float vals[DIM];
        const float4* ar = (const float4*)(a + (size_t)n * DIM);
        float4* er = (float4*)(emb + (size_t)n * DIM);
        #pragma unroll
        for (int c = 0; c < 5; ++c) {
            float4 v = ar[c];
            float r0 = fmaxf(v.x * sS[4*c+0] + sS[DIM + 4*c+0], 0.0f);
            float r1 = fmaxf(v.y * sS[4*c+1] + sS[DIM + 4*c+1], 0.0f);
            float r2 = fmaxf(v.z * sS[4*c+2] + sS[DIM + 4*c+2], 0.0f);
            float r3 = fmaxf(v.w * sS[4*c+3] + sS[DIM + 4*c+3], 0.0f);
            er[c] = make_float4(r0, r1, r2, r3);
            vals[4*c+0] = r0; vals[4*c+1] = r1; vals[4*c+2] = r2; vals[4*c+3] = r3;
        }
        if (uselds) {
            int base = (g - gmin) * DIM;
            #pragma unroll
            for (int jo = 0; jo < DIM; ++jo) {
                int j = (jo + tid) % DIM;
                atomicMax(&lmax[base + j], __float_as_uint(vals[j]));
            }
        } else {
            #pragma unroll
            for (int jo = 0; jo < DIM; ++jo) {
                int j = (jo + tid) % DIM;
                atomicMax(&ge[g * DIM + j], __float_as_uint(vals[j]));
            }
        }
    }
    __syncthreads();
    if (uselds) {
        for (int i = tid; i < gspan * DIM; i += 256) {
            unsigned int v = lmax[i];
            if (v) atomicMax(&ge[gmin * DIM + i], v);
        }
    }
}

// ---------------- fc head ----------------
__global__ __launch_bounds__(256) void fc_kernel(const float* __restrict__ ge, const float* __restrict__ fcW,
                                                 const float* __restrict__ fcb, float* __restrict__ out) {
    int gid = blockIdx.x * 256 + threadIdx.x;
    if (gid >= NGR * NCL) return;
    int g = gid >> 1, c = gid & 1;
    float acc = fcb[c];
    #pragma unroll
    for (int d = 0; d < DIM; ++d) acc += ge[g * DIM + d] * fcW[d * NCL + c];
    out[gid] = acc;
}

extern "C" void kernel_launch(void* const* d_in, const int* in_sizes, int n_in,
                              void* d_out, int out_size, void* d_ws, size_t ws_size,
                              hipStream_t stream) {
    const float* x    = (const float*)d_in[0];
    const int*   ei   = (const int*)d_in[1];
    const int*   src  = ei;
    const int*   dst  = ei + NE;
    const int*   batch = (const int*)d_in[2];
    const float* W0 = (const float*)d_in[3];  const float* b0 = (const float*)d_in[4];
    const float* g0 = (const float*)d_in[5];  const float* be0 = (const float*)d_in[6];
    const float* W1 = (const float*)d_in[7];  const float* b1 = (const float*)d_in[8];
    const float* g1 = (const float*)d_in[9];  const float* be1 = (const float*)d_in[10];
    const float* W2 = (const float*)d_in[11]; const float* b2 = (const float*)d_in[12];
    const float* g2 = (const float*)d_in[13]; const float* be2 = (const float*)d_in[14];
    const float* fcW = (const float*)d_in[15]; const float* fcb = (const float*)d_in[16];

    float* ws      = (float*)d_ws;
    float* dinv    = ws;                         // NN
    int*   cnt     = (int*)(ws + NN);            // NN (reused as cursor)
    int*   rowstart= (int*)(ws + 2 * NN);        // NN+1
    float* bufA    = ws + 3 * NN + 4;            // NN*DIM (16B aligned)
    float* bufB    = bufA + NN * DIM;            // NN*DIM
    int*   col     = (int*)(bufB + NN * DIM);    // NE
    float* stats   = (float*)(col + NE);         // 192
    float* ss      = stats + 192;                // 120
    int*   bsum    = (int*)(ss + 120);           // NB_SCAN

    float* emb    = (float*)d_out;               // NN*DIM
    float* ge     = emb + NN * DIM;              // NGR*DIM
    float* logits = ge + NGR * DIM;              // NGR*NCL

    const int E_BLKS = NE / 256;                 // 15625
    const int N_BLKS = (NN + 255) / 256;         // 782
    const int G_BLKS = (NN + 127) / 128;         // 1563

    hipMemsetAsync(cnt, 0, NN * sizeof(int), stream);
    hipMemsetAsync(stats, 0, 192 * sizeof(float), stream);
    hipMemsetAsync(ge, 0, NGR * DIM * sizeof(float), stream);

    // ---- CSR build (once; topology shared by all 3 layers) ----
    deg_kernel<<<E_BLKS, 256, 0, stream>>>(dst, cnt);
    dinv_kernel<<<N_BLKS, 256, 0, stream>>>(cnt, dinv);
    scan1_kernel<<<NB_SCAN, 256, 0, stream>>>(cnt, bsum);
    scan2_kernel<<<1, 1024, 0, stream>>>(bsum);
    scan3_kernel<<<NB_SCAN, 256, 0, stream>>>(cnt, bsum, rowstart);
    hipMemsetAsync(cnt, 0, NN * sizeof(int), stream);   // cnt -> cursor
    place_kernel<<<E_BLKS, 256, 0, stream>>>(src, dst, rowstart, cnt, col);

    lin0_kernel<<<NN / 64, 256, 0, stream>>>(x, W0, bufA);

    // layer 0
    gather_kernel<<<G_BLKS, 256, 0, stream>>>(bufA, col, rowstart, dinv, b0, bufB, stats);
    bn_param_kernel<<<1, 32, 0, stream>>>(stats, g0, be0, ss);
    lin_next_kernel<<<NN / 64, 256, 0, stream>>>(bufB, ss, W1, bufA);

    // layer 1
    gather_kernel<<<G_BLKS, 256, 0, stream>>>(bufA, col, rowstart, dinv, b1, bufB, stats + 64);
    bn_param_kernel<<<1, 32, 0, stream>>>(stats + 64, g1, be1, ss + 40);
    lin_next_kernel<<<NN / 64, 256, 0, stream>>>(bufB, ss + 40, W2, bufA);

    // layer 2
    gather_kernel<<<G_BLKS, 256, 0, stream>>>(bufA, col, rowstart, dinv, b2, bufB, stats + 128);
    bn_param_kernel<<<1, 32, 0, stream>>>(stats + 128, g2, be2, ss + 80);

    final_kernel<<<N_BLKS, 256, 0, stream>>>(bufB, ss + 80, batch, emb, (unsigned int*)ge);
    fc_kernel<<<(NGR * NCL + 255) / 256, 256, 0, stream>>>(ge, fcW, fcb, logits);
}

// Round 4
// 783.307 us; speedup vs baseline: 8.0496x; 1.2097x over previous
//
#include <hip/hip_runtime.h>

#define NN 200000
#define NE 4000000
#define FIN 64
#define DIM 20
#define NGR 512
#define NCL 2
#define BN_EPS 1e-5f
#define NB_SCAN 782   // ceil(NN/256)

// ---------------- degree + per-edge rank within dst ----------------
__global__ __launch_bounds__(256) void deg_rank_kernel(const int* __restrict__ dst, int* __restrict__ cnt,
                                                       int* __restrict__ rank) {
    int e = blockIdx.x * 256 + threadIdx.x;
    if (e < NE) rank[e] = atomicAdd(&cnt[dst[e]], 1);
}

__global__ __launch_bounds__(256) void dinv_kernel(const int* __restrict__ cnt, float* __restrict__ dinv) {
    int n = blockIdx.x * 256 + threadIdx.x;
    if (n < NN) dinv[n] = rsqrtf(1.0f + (float)cnt[n]);
}

// ---------------- 3-phase exclusive scan of cnt -> rowstart ----------------
__global__ __launch_bounds__(256) void scan1_kernel(const int* __restrict__ cnt, int* __restrict__ bsum) {
    int i = blockIdx.x * 256 + threadIdx.x;
    int v = (i < NN) ? cnt[i] : 0;
    #pragma unroll
    for (int off = 32; off > 0; off >>= 1) v += __shfl_down(v, off, 64);
    __shared__ int ws[4];
    if ((threadIdx.x & 63) == 0) ws[threadIdx.x >> 6] = v;
    __syncthreads();
    if (threadIdx.x == 0) bsum[blockIdx.x] = ws[0] + ws[1] + ws[2] + ws[3];
}

__global__ __launch_bounds__(1024) void scan2_kernel(int* __restrict__ bsum) {
    __shared__ int tmp[1024];
    int t = threadIdx.x;
    int v = (t < NB_SCAN) ? bsum[t] : 0;
    tmp[t] = v;
    __syncthreads();
    for (int off = 1; off < 1024; off <<= 1) {
        int u = (t >= off) ? tmp[t - off] : 0;
        __syncthreads();
        tmp[t] += u;
        __syncthreads();
    }
    if (t < NB_SCAN) bsum[t] = tmp[t] - v;   // exclusive
}

__global__ __launch_bounds__(256) void scan3_kernel(const int* __restrict__ cnt, const int* __restrict__ bsum,
                                                    int* __restrict__ rowstart) {
    __shared__ int tmp[256];
    int t = threadIdx.x;
    int i = blockIdx.x * 256 + t;
    int v = (i < NN) ? cnt[i] : 0;
    tmp[t] = v;
    __syncthreads();
    for (int off = 1; off < 256; off <<= 1) {
        int u = (t >= off) ? tmp[t - off] : 0;
        __syncthreads();
        tmp[t] += u;
        __syncthreads();
    }
    int incl = tmp[t];
    int base = bsum[blockIdx.x];
    if (i < NN) rowstart[i] = base + incl - v;
    if (i == NN - 1) rowstart[NN] = base + incl;
}

// ---------------- CSR placement (atomic-free) ----------------
__global__ __launch_bounds__(256) void place_kernel(const int* __restrict__ src, const int* __restrict__ dst,
                                                    const int* __restrict__ rowstart, const int* __restrict__ rank,
                                                    int* __restrict__ col) {
    int e = blockIdx.x * 256 + threadIdx.x;
    if (e >= NE) return;
    int pos = rowstart[dst[e]] + rank[e];
    __builtin_nontemporal_store(src[e], &col[pos]);
}

// ---------------- layer0 linear: y = (x @ W0) * dinv ----------------
__global__ __launch_bounds__(256) void lin0_kernel(const float* __restrict__ x, const float* __restrict__ W,
                                                   const float* __restrict__ dinv, float* __restrict__ out) {
    __shared__ float sW[FIN * DIM];
    __shared__ float sX[64 * 65];
    int tid = threadIdx.x;
    for (int i = tid; i < FIN * DIM; i += 256) sW[i] = W[i];
    int n0 = blockIdx.x * 64;
    #pragma unroll
    for (int k = 0; k < 16; ++k) {
        int idx = tid + k * 256;
        int row = idx >> 6, colf = idx & 63;
        sX[row * 65 + colf] = x[(n0 + row) * FIN + colf];
    }
    __syncthreads();
    int nl = tid & 63, wq = tid >> 6;
    float acc[5] = {0.f, 0.f, 0.f, 0.f, 0.f};
    for (int f = 0; f < FIN; ++f) {
        float xv = sX[nl * 65 + f];
        #pragma unroll
        for (int k = 0; k < 5; ++k) acc[k] += xv * sW[f * DIM + wq + 4 * k];
    }
    int n = n0 + nl;
    float dv = dinv[n];
    #pragma unroll
    for (int k = 0; k < 5; ++k) out[n * DIM + wq + 4 * k] = acc[k] * dv;
}

// ---------------- CSR gather on pre-scaled rows: agg = dinv*(sum+self) + b ----------------
__global__ __launch_bounds__(256) void gather_kernel(const float* __restrict__ y, const int* __restrict__ col,
                                                     const int* __restrict__ rowstart, const float* __restrict__ dinv,
                                                     const float* __restrict__ b, float* __restrict__ agg,
                                                     float* __restrict__ stats) {
    __shared__ float ls[2 * DIM];
    int tid = threadIdx.x;
    if (tid < 2 * DIM) ls[tid] = 0.f;
    __syncthreads();
    int n = blockIdx.x * 128 + (tid >> 1);
    int half = tid & 1;
    float acc[DIM];
    if (n < NN) {
        float di = dinv[n];
        if (half == 0) {   // self-loop: y[n] (scale di applied at the end)
            const float4* xr = (const float4*)(y + (size_t)n * DIM);
            #pragma unroll
            for (int c = 0; c < 5; ++c) {
                float4 v = xr[c];
                acc[4*c+0] = v.x; acc[4*c+1] = v.y; acc[4*c+2] = v.z; acc[4*c+3] = v.w;
            }
        } else {
            #pragma unroll
            for (int j = 0; j < DIM; ++j) acc[j] = 0.f;
        }
        int beg = rowstart[n], end = rowstart[n + 1];
        for (int e = beg + half; e < end; e += 2) {
            int s = col[e];
            const float4* xs = (const float4*)(y + (size_t)s * DIM);
            #pragma unroll
            for (int c = 0; c < 5; ++c) {
                float4 v = xs[c];
                acc[4*c+0] += v.x; acc[4*c+1] += v.y; acc[4*c+2] += v.z; acc[4*c+3] += v.w;
            }
        }
        #pragma unroll
        for (int j = 0; j < DIM; ++j) {
            acc[j] += __shfl_xor(acc[j], 1, 64);
            acc[j] = acc[j] * di + b[j];
        }
        float4* ar = (float4*)(agg + (size_t)n * DIM);
        if (half == 0) {
            #pragma unroll
            for (int c = 0; c < 3; ++c) ar[c] = make_float4(acc[4*c+0], acc[4*c+1], acc[4*c+2], acc[4*c+3]);
        } else {
            #pragma unroll
            for (int c = 3; c < 5; ++c) ar[c] = make_float4(acc[4*c+0], acc[4*c+1], acc[4*c+2], acc[4*c+3]);
        }
        // stats: 10 feats per lane (pair covers all 20), rotated to spread LDS banks
        int pr = tid >> 1;
        #pragma unroll
        for (int jo = 0; jo < 10; ++jo) {
            int j = ((jo + pr) % 10) + 10 * half;
            atomicAdd(&ls[j], acc[j]);
            atomicAdd(&ls[DIM + j], acc[j] * acc[j]);
        }
    }
    __syncthreads();
    if (tid < 2 * DIM) atomicAdd(&stats[tid], ls[tid]);
}

__global__ void bn_param_kernel(const float* __restrict__ stats, const float* __restrict__ g,
                                const float* __restrict__ beta, float* __restrict__ ss) {
    int d = threadIdx.x;
    if (d < DIM) {
        float mean = stats[d] * (1.0f / NN);
        float var = stats[DIM + d] * (1.0f / NN) - mean * mean;
        float sc = g[d] * rsqrtf(var + BN_EPS);
        ss[d] = sc;
        ss[DIM + d] = beta[d] - mean * sc;
    }
}

// ---------------- next linear: y = (relu(bn(a)) @ W) * dinv ----------------
__global__ __launch_bounds__(256) void lin_next_kernel(const float* __restrict__ a, const float* __restrict__ ss,
                                                       const float* __restrict__ W, const float* __restrict__ dinv,
                                                       float* __restrict__ out) {
    __shared__ float sW[DIM * DIM];
    __shared__ float sH[64 * 21];
    __shared__ float sS[2 * DIM];
    int tid = threadIdx.x;
    for (int i = tid; i < DIM * DIM; i += 256) sW[i] = W[i];
    if (tid < 2 * DIM) sS[tid] = ss[tid];
    __syncthreads();
    int n0 = blockIdx.x * 64;
    #pragma unroll
    for (int k = 0; k < 5; ++k) {
        int idx = tid + k * 256;
        int row = idx / DIM, colf = idx - row * DIM;
        float v = a[(n0 + row) * DIM + colf];
        sH[row * 21 + colf] = fmaxf(v * sS[colf] + sS[DIM + colf], 0.0f);
    }
    __syncthreads();
    int nl = tid & 63, wq = tid >> 6;
    float acc[5] = {0.f, 0.f, 0.f, 0.f, 0.f};
    for (int f = 0; f < DIM; ++f) {
        float h = sH[nl * 21 + f];
        #pragma unroll
        for (int k = 0; k < 5; ++k) acc[k] += h * sW[f * DIM + wq + 4 * k];
    }
    int n = n0 + nl;
    float dv = dinv[n];
    #pragma unroll
    for (int k = 0; k < 5; ++k) out[n * DIM + wq + 4 * k] = acc[k] * dv;
}

// ---------------- final: relu(bn) -> emb + segment_max (LDS pre-reduce; batch sorted) ----------------
__global__ __launch_bounds__(256) void final_kernel(const float* __restrict__ a, const float* __restrict__ ss,
                                                    const int* __restrict__ batch, float* __restrict__ emb,
                                                    unsigned int* __restrict__ ge) {
    __shared__ unsigned int lmax[8 * DIM];
    __shared__ float sS[2 * DIM];
    __shared__ int sg[2];
    int tid = threadIdx.x;
    if (tid < 2 * DIM) sS[tid] = ss[tid];
    int n0 = blockIdx.x * 256;
    if (tid == 0) {
        int nlast = min(n0 + 255, NN - 1);
        sg[0] = batch[n0];
        sg[1] = batch[nlast] - batch[n0] + 1;
    }
    for (int i = tid; i < 8 * DIM; i += 256) lmax[i] = 0u;
    __syncthreads();
    int gmin = sg[0], gspan = sg[1];
    bool uselds = (gspan <= 8);
    int n = n0 + tid;
    if (n < NN) {
        int g = batch[n];
        float vals[DIM];
        const float4* ar = (const float4*)(a + (size_t)n * DIM);
        float4* er = (float4*)(emb + (size_t)n * DIM);
        #pragma unroll
        for (int c = 0; c < 5; ++c) {
            float4 v = ar[c];
            float r0 = fmaxf(v.x * sS[4*c+0] + sS[DIM + 4*c+0], 0.0f);
            float r1 = fmaxf(v.y * sS[4*c+1] + sS[DIM + 4*c+1], 0.0f);
            float r2 = fmaxf(v.z * sS[4*c+2] + sS[DIM + 4*c+2], 0.0f);
            float r3 = fmaxf(v.w * sS[4*c+3] + sS[DIM + 4*c+3], 0.0f);
            er[c] = make_float4(r0, r1, r2, r3);
            vals[4*c+0] = r0; vals[4*c+1] = r1; vals[4*c+2] = r2; vals[4*c+3] = r3;
        }
        if (uselds) {
            int base = (g - gmin) * DIM;
            #pragma unroll
            for (int jo = 0; jo < DIM; ++jo) {
                int j = (jo + tid) % DIM;
                atomicMax(&lmax[base + j], __float_as_uint(vals[j]));
            }
        } else {
            #pragma unroll
            for (int jo = 0; jo < DIM; ++jo) {
                int j = (jo + tid) % DIM;
                atomicMax(&ge[g * DIM + j], __float_as_uint(vals[j]));
            }
        }
    }
    __syncthreads();
    if (uselds) {
        for (int i = tid; i < gspan * DIM; i += 256) {
            unsigned int v = lmax[i];
            if (v) atomicMax(&ge[gmin * DIM + i], v);
        }
    }
}

// ---------------- fc head ----------------
__global__ __launch_bounds__(256) void fc_kernel(const float* __restrict__ ge, const float* __restrict__ fcW,
                                                 const float* __restrict__ fcb, float* __restrict__ out) {
    int gid = blockIdx.x * 256 + threadIdx.x;
    if (gid >= NGR * NCL) return;
    int g = gid >> 1, c = gid & 1;
    float acc = fcb[c];
    #pragma unroll
    for (int d = 0; d < DIM; ++d) acc += ge[g * DIM + d] * fcW[d * NCL + c];
    out[gid] = acc;
}

extern "C" void kernel_launch(void* const* d_in, const int* in_sizes, int n_in,
                              void* d_out, int out_size, void* d_ws, size_t ws_size,
                              hipStream_t stream) {
    const float* x    = (const float*)d_in[0];
    const int*   ei   = (const int*)d_in[1];
    const int*   src  = ei;
    const int*   dst  = ei + NE;
    const int*   batch = (const int*)d_in[2];
    const float* W0 = (const float*)d_in[3];  const float* b0 = (const float*)d_in[4];
    const float* g0 = (const float*)d_in[5];  const float* be0 = (const float*)d_in[6];
    const float* W1 = (const float*)d_in[7];  const float* b1 = (const float*)d_in[8];
    const float* g1 = (const float*)d_in[9];  const float* be1 = (const float*)d_in[10];
    const float* W2 = (const float*)d_in[11]; const float* b2 = (const float*)d_in[12];
    const float* g2 = (const float*)d_in[13]; const float* be2 = (const float*)d_in[14];
    const float* fcW = (const float*)d_in[15]; const float* fcb = (const float*)d_in[16];

    float* ws      = (float*)d_ws;
    float* dinv    = ws;                         // NN
    int*   cnt     = (int*)(ws + NN);            // NN
    int*   rowstart= (int*)(ws + 2 * NN);        // NN+1
    float* bufA    = ws + 3 * NN + 4;            // NN*DIM (16B aligned); aliased as rank before lin0
    float* bufB    = bufA + NN * DIM;            // NN*DIM
    int*   col     = (int*)(bufB + NN * DIM);    // NE
    float* stats   = (float*)(col + NE);         // 192
    float* ss      = stats + 192;                // 120
    int*   bsum    = (int*)(ss + 120);           // NB_SCAN

    int*   rank    = (int*)bufA;                 // NE ints == NN*DIM floats; dead after place_kernel

    float* emb    = (float*)d_out;               // NN*DIM
    float* ge     = emb + NN * DIM;              // NGR*DIM
    float* logits = ge + NGR * DIM;              // NGR*NCL

    const int E_BLKS = NE / 256;                 // 15625
    const int N_BLKS = (NN + 255) / 256;         // 782
    const int G_BLKS = (NN + 127) / 128;         // 1563

    hipMemsetAsync(cnt, 0, NN * sizeof(int), stream);
    hipMemsetAsync(stats, 0, 192 * sizeof(float), stream);
    hipMemsetAsync(ge, 0, NGR * DIM * sizeof(float), stream);

    // ---- CSR build (once; topology shared by all 3 layers) ----
    deg_rank_kernel<<<E_BLKS, 256, 0, stream>>>(dst, cnt, rank);
    dinv_kernel<<<N_BLKS, 256, 0, stream>>>(cnt, dinv);
    scan1_kernel<<<NB_SCAN, 256, 0, stream>>>(cnt, bsum);
    scan2_kernel<<<1, 1024, 0, stream>>>(bsum);
    scan3_kernel<<<NB_SCAN, 256, 0, stream>>>(cnt, bsum, rowstart);
    place_kernel<<<E_BLKS, 256, 0, stream>>>(src, dst, rowstart, rank, col);

    lin0_kernel<<<NN / 64, 256, 0, stream>>>(x, W0, dinv, bufA);   // overwrites rank (dead)

    // layer 0
    gather_kernel<<<G_BLKS, 256, 0, stream>>>(bufA, col, rowstart, dinv, b0, bufB, stats);
    bn_param_kernel<<<1, 32, 0, stream>>>(stats, g0, be0, ss);
    lin_next_kernel<<<NN / 64, 256, 0, stream>>>(bufB, ss, W1, dinv, bufA);

    // layer 1
    gather_kernel<<<G_BLKS, 256, 0, stream>>>(bufA, col, rowstart, dinv, b1, bufB, stats + 64);
    bn_param_kernel<<<1, 32, 0, stream>>>(stats + 64, g1, be1, ss + 40);
    lin_next_kernel<<<NN / 64, 256, 0, stream>>>(bufB, ss + 40, W2, dinv, bufA);

    // layer 2
    gather_kernel<<<G_BLKS, 256, 0, stream>>>(bufA, col, rowstart, dinv, b2, bufB, stats + 128);
    bn_param_kernel<<<1, 32, 0, stream>>>(stats + 128, g2, be2, ss + 80);

    final_kernel<<<N_BLKS, 256, 0, stream>>>(bufB, ss + 80, batch, emb, (unsigned int*)ge);
    fc_kernel<<<(NGR * NCL + 255) / 256, 256, 0, stream>>>(ge, fcW, fcb, logits);
}

// Round 5
// 768.825 us; speedup vs baseline: 8.2012x; 1.0188x over previous
//
#include <hip/hip_runtime.h>

#define NN 200000
#define NE 4000000
#define FIN 64
#define DIM 20
#define NGR 512
#define NCL 2
#define BN_EPS 1e-5f
#define NB_SCAN 782            // ceil(NN/256)
#define RNG (NN / 8)           // 25000 dst per residue class
#define NWIN ((NE + 2047) / 2048)   // 1954 edge windows
#define GRID_FILTER (NWIN * 8)      // 15632

// ---------------- degree count, dst-range partitioned (XCD-local atomics) ----------------
__global__ __launch_bounds__(256) void count_kernel(const int* __restrict__ dst, int* __restrict__ cnt) {
    int b = blockIdx.x;
    int r = b & 7, win = b >> 3;
    int lo = r * RNG;
    int e0 = win * 2048 + threadIdx.x * 8;
    if (e0 + 8 <= NE) {
        int4 d0 = *(const int4*)(dst + e0);
        int4 d1 = *(const int4*)(dst + e0 + 4);
        int t;
        t = d0.x; if ((unsigned)(t - lo) < RNG) atomicAdd(&cnt[t], 1);
        t = d0.y; if ((unsigned)(t - lo) < RNG) atomicAdd(&cnt[t], 1);
        t = d0.z; if ((unsigned)(t - lo) < RNG) atomicAdd(&cnt[t], 1);
        t = d0.w; if ((unsigned)(t - lo) < RNG) atomicAdd(&cnt[t], 1);
        t = d1.x; if ((unsigned)(t - lo) < RNG) atomicAdd(&cnt[t], 1);
        t = d1.y; if ((unsigned)(t - lo) < RNG) atomicAdd(&cnt[t], 1);
        t = d1.z; if ((unsigned)(t - lo) < RNG) atomicAdd(&cnt[t], 1);
        t = d1.w; if ((unsigned)(t - lo) < RNG) atomicAdd(&cnt[t], 1);
    } else {
        for (int k = 0; k < 8; ++k) {
            int e = e0 + k;
            if (e < NE) { int t = dst[e]; if ((unsigned)(t - lo) < RNG) atomicAdd(&cnt[t], 1); }
        }
    }
}

__global__ __launch_bounds__(256) void dinv_kernel(const int* __restrict__ cnt, float* __restrict__ dinv) {
    int n = blockIdx.x * 256 + threadIdx.x;
    if (n < NN) dinv[n] = rsqrtf(1.0f + (float)cnt[n]);
}

// ---------------- 3-phase exclusive scan of cnt -> rowstart ----------------
__global__ __launch_bounds__(256) void scan1_kernel(const int* __restrict__ cnt, int* __restrict__ bsum) {
    int i = blockIdx.x * 256 + threadIdx.x;
    int v = (i < NN) ? cnt[i] : 0;
    #pragma unroll
    for (int off = 32; off > 0; off >>= 1) v += __shfl_down(v, off, 64);
    __shared__ int ws[4];
    if ((threadIdx.x & 63) == 0) ws[threadIdx.x >> 6] = v;
    __syncthreads();
    if (threadIdx.x == 0) bsum[blockIdx.x] = ws[0] + ws[1] + ws[2] + ws[3];
}

__global__ __launch_bounds__(1024) void scan2_kernel(int* __restrict__ bsum) {
    __shared__ int tmp[1024];
    int t = threadIdx.x;
    int v = (t < NB_SCAN) ? bsum[t] : 0;
    tmp[t] = v;
    __syncthreads();
    for (int off = 1; off < 1024; off <<= 1) {
        int u = (t >= off) ? tmp[t - off] : 0;
        __syncthreads();
        tmp[t] += u;
        __syncthreads();
    }
    if (t < NB_SCAN) bsum[t] = tmp[t] - v;   // exclusive
}

__global__ __launch_bounds__(256) void scan3_kernel(const int* __restrict__ cnt, const int* __restrict__ bsum,
                                                    int* __restrict__ rowstart) {
    __shared__ int tmp[256];
    int t = threadIdx.x;
    int i = blockIdx.x * 256 + t;
    int v = (i < NN) ? cnt[i] : 0;
    tmp[t] = v;
    __syncthreads();
    for (int off = 1; off < 256; off <<= 1) {
        int u = (t >= off) ? tmp[t - off] : 0;
        __syncthreads();
        tmp[t] += u;
        __syncthreads();
    }
    if (i < NN) rowstart[i] = bsum[blockIdx.x] + tmp[t] - v;
}

// ---------------- CSR placement, dst-range partitioned; rowstart doubles as cursor ----------------
// After this kernel rowstart[n] == original rowstart[n+1] (row end).
__global__ __launch_bounds__(256) void place_kernel(const int* __restrict__ src, const int* __restrict__ dst,
                                                    int* __restrict__ rowcur, int* __restrict__ col) {
    int b = blockIdx.x;
    int r = b & 7, win = b >> 3;
    int lo = r * RNG;
    int e0 = win * 2048 + threadIdx.x * 8;
    if (e0 + 8 <= NE) {
        int4 d0 = *(const int4*)(dst + e0);
        int4 d1 = *(const int4*)(dst + e0 + 4);
        int4 s0 = *(const int4*)(src + e0);
        int4 s1 = *(const int4*)(src + e0 + 4);
        int t;
        t = d0.x; if ((unsigned)(t - lo) < RNG) col[atomicAdd(&rowcur[t], 1)] = s0.x;
        t = d0.y; if ((unsigned)(t - lo) < RNG) col[atomicAdd(&rowcur[t], 1)] = s0.y;
        t = d0.z; if ((unsigned)(t - lo) < RNG) col[atomicAdd(&rowcur[t], 1)] = s0.z;
        t = d0.w; if ((unsigned)(t - lo) < RNG) col[atomicAdd(&rowcur[t], 1)] = s0.w;
        t = d1.x; if ((unsigned)(t - lo) < RNG) col[atomicAdd(&rowcur[t], 1)] = s1.x;
        t = d1.y; if ((unsigned)(t - lo) < RNG) col[atomicAdd(&rowcur[t], 1)] = s1.y;
        t = d1.z; if ((unsigned)(t - lo) < RNG) col[atomicAdd(&rowcur[t], 1)] = s1.z;
        t = d1.w; if ((unsigned)(t - lo) < RNG) col[atomicAdd(&rowcur[t], 1)] = s1.w;
    } else {
        for (int k = 0; k < 8; ++k) {
            int e = e0 + k;
            if (e < NE) {
                int t = dst[e];
                if ((unsigned)(t - lo) < RNG) col[atomicAdd(&rowcur[t], 1)] = src[e];
            }
        }
    }
}

// ---------------- layer0 linear: y = (x @ W0) * dinv ----------------
template<int S>
__global__ __launch_bounds__(256) void lin0_kernel(const float* __restrict__ x, const float* __restrict__ W,
                                                   const float* __restrict__ dinv, float* __restrict__ out) {
    __shared__ float sW[FIN * DIM];
    __shared__ float sX[64 * 65];
    int tid = threadIdx.x;
    for (int i = tid; i < FIN * DIM; i += 256) sW[i] = W[i];
    int n0 = blockIdx.x * 64;
    #pragma unroll
    for (int k = 0; k < 16; ++k) {
        int idx = tid + k * 256;
        int row = idx >> 6, colf = idx & 63;
        sX[row * 65 + colf] = x[(n0 + row) * FIN + colf];
    }
    __syncthreads();
    int nl = tid & 63, wq = tid >> 6;
    float acc[5] = {0.f, 0.f, 0.f, 0.f, 0.f};
    for (int f = 0; f < FIN; ++f) {
        float xv = sX[nl * 65 + f];
        #pragma unroll
        for (int k = 0; k < 5; ++k) acc[k] += xv * sW[f * DIM + wq + 4 * k];
    }
    int n = n0 + nl;
    float dv = dinv[n];
    #pragma unroll
    for (int k = 0; k < 5; ++k) out[(size_t)n * S + wq + 4 * k] = acc[k] * dv;
}

// ---------------- CSR gather on pre-scaled rows: agg = dinv*(sum+self) + b ----------------
// rowstart is POST-PLACE: rowstart[n] = row end; beg = (n ? rowstart[n-1] : 0)
template<int S>
__global__ __launch_bounds__(256) void gather_kernel(const float* __restrict__ y, const int* __restrict__ col,
                                                     const int* __restrict__ rowstart, const float* __restrict__ dinv,
                                                     const float* __restrict__ b, float* __restrict__ agg,
                                                     float* __restrict__ stats) {
    __shared__ float ls[2 * DIM];
    int tid = threadIdx.x;
    if (tid < 2 * DIM) ls[tid] = 0.f;
    __syncthreads();
    int n = blockIdx.x * 128 + (tid >> 1);
    int half = tid & 1;
    float acc[DIM];
    if (n < NN) {
        float di = dinv[n];
        if (half == 0) {   // self-loop contribution y[n]
            const float4* xr = (const float4*)(y + (size_t)n * S);
            #pragma unroll
            for (int c = 0; c < 5; ++c) {
                float4 v = xr[c];
                acc[4*c+0] = v.x; acc[4*c+1] = v.y; acc[4*c+2] = v.z; acc[4*c+3] = v.w;
            }
        } else {
            #pragma unroll
            for (int j = 0; j < DIM; ++j) acc[j] = 0.f;
        }
        int beg = (n == 0) ? 0 : rowstart[n - 1];
        int end = rowstart[n];
        for (int e = beg + half; e < end; e += 2) {
            int s = col[e];
            const float4* xs = (const float4*)(y + (size_t)s * S);
            #pragma unroll
            for (int c = 0; c < 5; ++c) {
                float4 v = xs[c];
                acc[4*c+0] += v.x; acc[4*c+1] += v.y; acc[4*c+2] += v.z; acc[4*c+3] += v.w;
            }
        }
        #pragma unroll
        for (int j = 0; j < DIM; ++j) {
            acc[j] += __shfl_xor(acc[j], 1, 64);
            acc[j] = acc[j] * di + b[j];
        }
        float4* ar = (float4*)(agg + (size_t)n * S);
        if (half == 0) {
            #pragma unroll
            for (int c = 0; c < 3; ++c) ar[c] = make_float4(acc[4*c+0], acc[4*c+1], acc[4*c+2], acc[4*c+3]);
        } else {
            #pragma unroll
            for (int c = 3; c < 5; ++c) ar[c] = make_float4(acc[4*c+0], acc[4*c+1], acc[4*c+2], acc[4*c+3]);
        }
        int pr = tid >> 1;
        #pragma unroll
        for (int jo = 0; jo < 10; ++jo) {
            int j = ((jo + pr) % 10) + 10 * half;
            atomicAdd(&ls[j], acc[j]);
            atomicAdd(&ls[DIM + j], acc[j] * acc[j]);
        }
    }
    __syncthreads();
    if (tid < 2 * DIM) atomicAdd(&stats[tid], ls[tid]);
}

__global__ void bn_param_kernel(const float* __restrict__ stats, const float* __restrict__ g,
                                const float* __restrict__ beta, float* __restrict__ ss) {
    int d = threadIdx.x;
    if (d < DIM) {
        float mean = stats[d] * (1.0f / NN);
        float var = stats[DIM + d] * (1.0f / NN) - mean * mean;
        float sc = g[d] * rsqrtf(var + BN_EPS);
        ss[d] = sc;
        ss[DIM + d] = beta[d] - mean * sc;
    }
}

// ---------------- next linear: y = (relu(bn(a)) @ W) * dinv ----------------
template<int S>
__global__ __launch_bounds__(256) void lin_next_kernel(const float* __restrict__ a, const float* __restrict__ ss,
                                                       const float* __restrict__ W, const float* __restrict__ dinv,
                                                       float* __restrict__ out) {
    __shared__ float sW[DIM * DIM];
    __shared__ float sH[64 * 21];
    __shared__ float sS[2 * DIM];
    int tid = threadIdx.x;
    for (int i = tid; i < DIM * DIM; i += 256) sW[i] = W[i];
    if (tid < 2 * DIM) sS[tid] = ss[tid];
    __syncthreads();
    int n0 = blockIdx.x * 64;
    #pragma unroll
    for (int k = 0; k < 5; ++k) {
        int idx = tid + k * 256;
        int row = idx / DIM, colf = idx - row * DIM;
        float v = a[(size_t)(n0 + row) * S + colf];
        sH[row * 21 + colf] = fmaxf(v * sS[colf] + sS[DIM + colf], 0.0f);
    }
    __syncthreads();
    int nl = tid & 63, wq = tid >> 6;
    float acc[5] = {0.f, 0.f, 0.f, 0.f, 0.f};
    for (int f = 0; f < DIM; ++f) {
        float h = sH[nl * 21 + f];
        #pragma unroll
        for (int k = 0; k < 5; ++k) acc[k] += h * sW[f * DIM + wq + 4 * k];
    }
    int n = n0 + nl;
    float dv = dinv[n];
    #pragma unroll
    for (int k = 0; k < 5; ++k) out[(size_t)n * S + wq + 4 * k] = acc[k] * dv;
}

// ---------------- final: relu(bn) -> emb (packed DIM) + segment_max ----------------
template<int S>
__global__ __launch_bounds__(256) void final_kernel(const float* __restrict__ a, const float* __restrict__ ss,
                                                    const int* __restrict__ batch, float* __restrict__ emb,
                                                    unsigned int* __restrict__ ge) {
    __shared__ unsigned int lmax[8 * DIM];
    __shared__ float sS[2 * DIM];
    __shared__ int sg[2];
    int tid = threadIdx.x;
    if (tid < 2 * DIM) sS[tid] = ss[tid];
    int n0 = blockIdx.x * 256;
    if (tid == 0) {
        int nlast = min(n0 + 255, NN - 1);
        sg[0] = batch[n0];
        sg[1] = batch[nlast] - batch[n0] + 1;
    }
    for (int i = tid; i < 8 * DIM; i += 256) lmax[i] = 0u;
    __syncthreads();
    int gmin = sg[0], gspan = sg[1];
    bool uselds = (gspan <= 8);
    int n = n0 + tid;
    if (n < NN) {
        int g = batch[n];
        float vals[DIM];
        const float4* ar = (const float4*)(a + (size_t)n * S);
        float4* er = (float4*)(emb + (size_t)n * DIM);
        #pragma unroll
        for (int c = 0; c < 5; ++c) {
            float4 v = ar[c];
            float r0 = fmaxf(v.x * sS[4*c+0] + sS[DIM + 4*c+0], 0.0f);
            float r1 = fmaxf(v.y * sS[4*c+1] + sS[DIM + 4*c+1], 0.0f);
            float r2 = fmaxf(v.z * sS[4*c+2] + sS[DIM + 4*c+2], 0.0f);
            float r3 = fmaxf(v.w * sS[4*c+3] + sS[DIM + 4*c+3], 0.0f);
            er[c] = make_float4(r0, r1, r2, r3);
            vals[4*c+0] = r0; vals[4*c+1] = r1; vals[4*c+2] = r2; vals[4*c+3] = r3;
        }
        if (uselds) {
            int base = (g - gmin) * DIM;
            #pragma unroll
            for (int jo = 0; jo < DIM; ++jo) {
                int j = (jo + tid) % DIM;
                atomicMax(&lmax[base + j], __float_as_uint(vals[j]));
            }
        } else {
            #pragma unroll
            for (int jo = 0; jo < DIM; ++jo) {
                int j = (jo + tid) % DIM;
                atomicMax(&ge[g * DIM + j], __float_as_uint(vals[j]));
            }
        }
    }
    __syncthreads();
    if (uselds) {
        for (int i = tid; i < gspan * DIM; i += 256) {
            unsigned int v = lmax[i];
            if (v) atomicMax(&ge[gmin * DIM + i], v);
        }
    }
}

// ---------------- fc head ----------------
__global__ __launch_bounds__(256) void fc_kernel(const float* __restrict__ ge, const float* __restrict__ fcW,
                                                 const float* __restrict__ fcb, float* __restrict__ out) {
    int gid = blockIdx.x * 256 + threadIdx.x;
    if (gid >= NGR * NCL) return;
    int g = gid >> 1, c = gid & 1;
    float acc = fcb[c];
    #pragma unroll
    for (int d = 0; d < DIM; ++d) acc += ge[g * DIM + d] * fcW[d * NCL + c];
    out[gid] = acc;
}

template<int S>
static void run_pipeline(const float* x, const int* src, const int* dst, const int* batch,
                         const float* W0, const float* b0, const float* g0, const float* be0,
                         const float* W1, const float* b1, const float* g1, const float* be1,
                         const float* W2, const float* b2, const float* g2, const float* be2,
                         const float* fcW, const float* fcb,
                         float* ws, float* emb, float* ge, float* logits, hipStream_t stream) {
    float* dinv     = ws;                        // NN
    int*   cnt      = (int*)(ws + NN);           // NN
    int*   rowstart = (int*)(ws + 2 * NN);       // NN (becomes row-end after place)
    float* bufA     = ws + 3 * NN + 4;           // NN*S (16B aligned)
    float* bufB     = bufA + (size_t)NN * S;     // NN*S
    int*   col      = (int*)(bufB + (size_t)NN * S);  // NE
    float* stats    = (float*)(col + NE);        // 192
    float* ss       = stats + 192;               // 120
    int*   bsum     = (int*)(ss + 120);          // NB_SCAN

    const int N_BLKS = (NN + 255) / 256;         // 782
    const int G_BLKS = (NN + 127) / 128;         // 1563

    hipMemsetAsync(cnt, 0, NN * sizeof(int), stream);
    hipMemsetAsync(stats, 0, 192 * sizeof(float), stream);
    hipMemsetAsync(ge, 0, NGR * DIM * sizeof(float), stream);

    // ---- CSR build (XCD-local by dst range) ----
    count_kernel<<<GRID_FILTER, 256, 0, stream>>>(dst, cnt);
    dinv_kernel<<<N_BLKS, 256, 0, stream>>>(cnt, dinv);
    scan1_kernel<<<NB_SCAN, 256, 0, stream>>>(cnt, bsum);
    scan2_kernel<<<1, 1024, 0, stream>>>(bsum);
    scan3_kernel<<<NB_SCAN, 256, 0, stream>>>(cnt, bsum, rowstart);
    place_kernel<<<GRID_FILTER, 256, 0, stream>>>(src, dst, rowstart, col);

    lin0_kernel<S><<<NN / 64, 256, 0, stream>>>(x, W0, dinv, bufA);

    gather_kernel<S><<<G_BLKS, 256, 0, stream>>>(bufA, col, rowstart, dinv, b0, bufB, stats);
    bn_param_kernel<<<1, 32, 0, stream>>>(stats, g0, be0, ss);
    lin_next_kernel<S><<<NN / 64, 256, 0, stream>>>(bufB, ss, W1, dinv, bufA);

    gather_kernel<S><<<G_BLKS, 256, 0, stream>>>(bufA, col, rowstart, dinv, b1, bufB, stats + 64);
    bn_param_kernel<<<1, 32, 0, stream>>>(stats + 64, g1, be1, ss + 40);
    lin_next_kernel<S><<<NN / 64, 256, 0, stream>>>(bufB, ss + 40, W2, dinv, bufA);

    gather_kernel<S><<<G_BLKS, 256, 0, stream>>>(bufA, col, rowstart, dinv, b2, bufB, stats + 128);
    bn_param_kernel<<<1, 32, 0, stream>>>(stats + 128, g2, be2, ss + 80);

    final_kernel<S><<<N_BLKS, 256, 0, stream>>>(bufB, ss + 80, batch, emb, (unsigned int*)ge);
    fc_kernel<<<(NGR * NCL + 255) / 256, 256, 0, stream>>>(ge, fcW, fcb, logits);
}

extern "C" void kernel_launch(void* const* d_in, const int* in_sizes, int n_in,
                              void* d_out, int out_size, void* d_ws, size_t ws_size,
                              hipStream_t stream) {
    const float* x     = (const float*)d_in[0];
    const int*   ei    = (const int*)d_in[1];
    const int*   src   = ei;
    const int*   dst   = ei + NE;
    const int*   batch = (const int*)d_in[2];
    const float* W0 = (const float*)d_in[3];  const float* b0 = (const float*)d_in[4];
    const float* g0 = (const float*)d_in[5];  const float* be0 = (const float*)d_in[6];
    const float* W1 = (const float*)d_in[7];  const float* b1 = (const float*)d_in[8];
    const float* g1 = (const float*)d_in[9];  const float* be1 = (const float*)d_in[10];
    const float* W2 = (const float*)d_in[11]; const float* b2 = (const float*)d_in[12];
    const float* g2 = (const float*)d_in[13]; const float* be2 = (const float*)d_in[14];
    const float* fcW = (const float*)d_in[15]; const float* fcb = (const float*)d_in[16];

    float* ws     = (float*)d_ws;
    float* emb    = (float*)d_out;               // NN*DIM (packed)
    float* ge     = emb + (size_t)NN * DIM;      // NGR*DIM
    float* logits = ge + NGR * DIM;              // NGR*NCL

    // ws need (floats): 3*NN+4 + 2*NN*S + NE + 1094
    const size_t need32 = ((size_t)3 * NN + 4 + (size_t)2 * NN * 32 + NE + 1094) * 4;
    if (ws_size >= need32) {
        run_pipeline<32>(x, src, dst, batch, W0, b0, g0, be0, W1, b1, g1, be1,
                         W2, b2, g2, be2, fcW, fcb, ws, emb, ge, logits, stream);
    } else {
        run_pipeline<20>(x, src, dst, batch, W0, b0, g0, be0, W1, b1, g1, be1,
                         W2, b2, g2, be2, fcW, fcb, ws, emb, ge, logits, stream);
    }
}

// Round 6
// 524.671 us; speedup vs baseline: 12.0176x; 1.4653x over previous
//
#include <hip/hip_runtime.h>

#define NN 200000
#define NE 4000000
#define FIN 64
#define DIM 20
#define NGR 512
#define NCL 2
#define BN_EPS 1e-5f

#define BKT 391                 // buckets of 512 nodes (dst>>9); 391*512 >= NN
#define BNODE 512
#define NCTR (8 * BKT)          // per-(xcd,bucket) counters
#define T2 32768                // edges per multisplit tile
#define NT2 ((NE + T2 - 1) / T2)  // 123

// ---------------- pass 1: per-(xcd,bucket) edge histogram ----------------
__global__ __launch_bounds__(256) void hist_kernel(const int* __restrict__ dst, int* __restrict__ ghist) {
    __shared__ int h[BKT];
    int t = threadIdx.x;
    for (int i = t; i < BKT; i += 256) h[i] = 0;
    __syncthreads();
    size_t base = (size_t)blockIdx.x * T2;
    for (int kk = 0; kk < 32; ++kk) {
        size_t e = base + (size_t)kk * 1024 + t * 4;
        if (e + 4 <= NE) {
            int4 d = *(const int4*)(dst + e);
            atomicAdd(&h[d.x >> 9], 1);
            atomicAdd(&h[d.y >> 9], 1);
            atomicAdd(&h[d.z >> 9], 1);
            atomicAdd(&h[d.w >> 9], 1);
        } else {
            for (int j = 0; j < 4; ++j)
                if (e + j < NE) atomicAdd(&h[dst[e + j] >> 9], 1);
        }
    }
    __syncthreads();
    int r = blockIdx.x & 7;   // XCD residue (round-robin dispatch heuristic)
    for (int i = t; i < BKT; i += 256)
        if (h[i]) atomicAdd(&ghist[r * BKT + i], h[i]);
}

// ---------------- pass 2: scan 3128 counters -> bbase[(b,r) order], bcur[[r][b] layout] ----------------
__global__ __launch_bounds__(1024) void scan_small_kernel(const int* __restrict__ ghist,
                                                          int* __restrict__ bbase, int* __restrict__ bcur) {
    __shared__ int c[1024];
    int t = threadIdx.x;
    int v[4];
    int sum = 0;
    #pragma unroll
    for (int j = 0; j < 4; ++j) {
        int idx = t * 4 + j;                 // logical order: idx = b*8 + r
        int x = 0;
        if (idx < NCTR) x = ghist[(idx & 7) * BKT + (idx >> 3)];
        v[j] = x; sum += x;
    }
    c[t] = sum;
    __syncthreads();
    for (int off = 1; off < 1024; off <<= 1) {
        int u = (t >= off) ? c[t - off] : 0;
        __syncthreads();
        c[t] += u;
        __syncthreads();
    }
    int run = (t == 0) ? 0 : c[t - 1];
    #pragma unroll
    for (int j = 0; j < 4; ++j) {
        int idx = t * 4 + j;
        if (idx < NCTR) {
            bbase[idx] = run;
            bcur[(idx & 7) * BKT + (idx >> 3)] = run;   // cursor in [r][b] layout (XCD-local lines)
        }
        run += v[j];
    }
    if (t == 1023) bbase[NCTR] = run;        // == NE
}

// ---------------- pass 3: multisplit scatter into bucket-ordered packed[] ----------------
__global__ __launch_bounds__(256) void p2_kernel(const int* __restrict__ src, const int* __restrict__ dst,
                                                 int* __restrict__ bcur, unsigned int* __restrict__ packed) {
    __shared__ int h[BKT], gb[BKT], lc[BKT];
    int t = threadIdx.x;
    for (int i = t; i < BKT; i += 256) { h[i] = 0; lc[i] = 0; }
    __syncthreads();
    size_t base = (size_t)blockIdx.x * T2;
    // phase 1: tile histogram
    for (int kk = 0; kk < 32; ++kk) {
        size_t e = base + (size_t)kk * 1024 + t * 4;
        if (e + 4 <= NE) {
            int4 d = *(const int4*)(dst + e);
            atomicAdd(&h[d.x >> 9], 1);
            atomicAdd(&h[d.y >> 9], 1);
            atomicAdd(&h[d.z >> 9], 1);
            atomicAdd(&h[d.w >> 9], 1);
        } else {
            for (int j = 0; j < 4; ++j)
                if (e + j < NE) atomicAdd(&h[dst[e + j] >> 9], 1);
        }
    }
    __syncthreads();
    // phase 2: one reservation per (tile,bucket) on XCD-local cursor
    int r = blockIdx.x & 7;
    for (int i = t; i < BKT; i += 256)
        gb[i] = h[i] ? atomicAdd(&bcur[r * BKT + i], h[i]) : 0;
    __syncthreads();
    // phase 3: scatter (writes cluster ~84 contiguous per bucket per tile)
    for (int kk = 0; kk < 32; ++kk) {
        size_t e = base + (size_t)kk * 1024 + t * 4;
        if (e + 4 <= NE) {
            int4 d = *(const int4*)(dst + e);
            int4 s = *(const int4*)(src + e);
            int b, p;
            b = d.x >> 9; p = gb[b] + atomicAdd(&lc[b], 1); packed[p] = ((unsigned)s.x << 9) | (unsigned)(d.x & 511);
            b = d.y >> 9; p = gb[b] + atomicAdd(&lc[b], 1); packed[p] = ((unsigned)s.y << 9) | (unsigned)(d.y & 511);
            b = d.z >> 9; p = gb[b] + atomicAdd(&lc[b], 1); packed[p] = ((unsigned)s.z << 9) | (unsigned)(d.z & 511);
            b = d.w >> 9; p = gb[b] + atomicAdd(&lc[b], 1); packed[p] = ((unsigned)s.w << 9) | (unsigned)(d.w & 511);
        } else {
            for (int j = 0; j < 4; ++j) {
                if (e + j < NE) {
                    int dd = dst[e + j], ss_ = src[e + j];
                    int b = dd >> 9;
                    int p = gb[b] + atomicAdd(&lc[b], 1);
                    packed[p] = ((unsigned)ss_ << 9) | (unsigned)(dd & 511);
                }
            }
        }
    }
}

// ---------------- pass 4: per-bucket CSR finalize (count, scan, place, dinv, rowstart) ----------------
__global__ __launch_bounds__(256) void p3_kernel(const unsigned int* __restrict__ packed, const int* __restrict__ bbase,
                                                 int* __restrict__ col, int* __restrict__ rowstart,
                                                 float* __restrict__ dinv) {
    __shared__ int lcnt[BNODE], lexc[BNODE], lcur[BNODE];
    __shared__ int tmp[256];
    int t = threadIdx.x;
    int b = blockIdx.x;
    for (int i = t; i < BNODE; i += 256) { lcnt[i] = 0; lcur[i] = 0; }
    __syncthreads();
    int beg = bbase[b * 8], end = bbase[(b + 1) * 8];
    for (int i = beg + t; i < end; i += 256) atomicAdd(&lcnt[packed[i] & 511], 1);
    __syncthreads();
    // exclusive scan of 512 with 256 threads (pair trick)
    int c2 = lcnt[2 * t] + lcnt[2 * t + 1];
    tmp[t] = c2;
    __syncthreads();
    for (int off = 1; off < 256; off <<= 1) {
        int u = (t >= off) ? tmp[t - off] : 0;
        __syncthreads();
        tmp[t] += u;
        __syncthreads();
    }
    int ex = (t == 0) ? 0 : tmp[t - 1];
    lexc[2 * t] = ex;
    lexc[2 * t + 1] = ex + lcnt[2 * t];
    __syncthreads();
    // place (block's 48KB col window stays L2-resident)
    for (int i = beg + t; i < end; i += 256) {
        unsigned int p = packed[i];
        int ld = p & 511;
        int pos = lexc[ld] + atomicAdd(&lcur[ld], 1);
        col[beg + pos] = (int)(p >> 9);
    }
    // node outputs (coalesced)
    int n0 = b * BNODE;
    for (int i = t; i < BNODE; i += 256) {
        int n = n0 + i;
        if (n < NN) {
            int c = lcnt[i];
            rowstart[n] = beg + lexc[i] + c;          // inclusive row end
            dinv[n] = rsqrtf(1.0f + (float)c);
        }
    }
}

// ---------------- layer0 linear: y = (x @ W0) * dinv ----------------
template<int S>
__global__ __launch_bounds__(256) void lin0_kernel(const float* __restrict__ x, const float* __restrict__ W,
                                                   const float* __restrict__ dinv, float* __restrict__ out) {
    __shared__ float sW[FIN * DIM];
    __shared__ float sX[64 * 65];
    int tid = threadIdx.x;
    for (int i = tid; i < FIN * DIM; i += 256) sW[i] = W[i];
    int n0 = blockIdx.x * 64;
    #pragma unroll
    for (int k = 0; k < 16; ++k) {
        int idx = tid + k * 256;
        int row = idx >> 6, colf = idx & 63;
        sX[row * 65 + colf] = x[(n0 + row) * FIN + colf];
    }
    __syncthreads();
    int nl = tid & 63, wq = tid >> 6;
    float acc[5] = {0.f, 0.f, 0.f, 0.f, 0.f};
    for (int f = 0; f < FIN; ++f) {
        float xv = sX[nl * 65 + f];
        #pragma unroll
        for (int k = 0; k < 5; ++k) acc[k] += xv * sW[f * DIM + wq + 4 * k];
    }
    int n = n0 + nl;
    float dv = dinv[n];
    #pragma unroll
    for (int k = 0; k < 5; ++k) out[(size_t)n * S + wq + 4 * k] = acc[k] * dv;
}

// ---------------- CSR gather on pre-scaled rows: agg = dinv*(sum+self) + b ----------------
template<int S>
__global__ __launch_bounds__(256) void gather_kernel(const float* __restrict__ y, const int* __restrict__ col,
                                                     const int* __restrict__ rowstart, const float* __restrict__ dinv,
                                                     const float* __restrict__ b, float* __restrict__ agg,
                                                     float* __restrict__ stats) {
    __shared__ float ls[2 * DIM];
    int tid = threadIdx.x;
    if (tid < 2 * DIM) ls[tid] = 0.f;
    __syncthreads();
    int n = blockIdx.x * 128 + (tid >> 1);
    int half = tid & 1;
    float acc[DIM];
    if (n < NN) {
        float di = dinv[n];
        if (half == 0) {
            const float4* xr = (const float4*)(y + (size_t)n * S);
            #pragma unroll
            for (int c = 0; c < 5; ++c) {
                float4 v = xr[c];
                acc[4*c+0] = v.x; acc[4*c+1] = v.y; acc[4*c+2] = v.z; acc[4*c+3] = v.w;
            }
        } else {
            #pragma unroll
            for (int j = 0; j < DIM; ++j) acc[j] = 0.f;
        }
        int beg = (n == 0) ? 0 : rowstart[n - 1];
        int end = rowstart[n];
        for (int e = beg + half; e < end; e += 2) {
            int s = col[e];
            const float4* xs = (const float4*)(y + (size_t)s * S);
            #pragma unroll
            for (int c = 0; c < 5; ++c) {
                float4 v = xs[c];
                acc[4*c+0] += v.x; acc[4*c+1] += v.y; acc[4*c+2] += v.z; acc[4*c+3] += v.w;
            }
        }
        #pragma unroll
        for (int j = 0; j < DIM; ++j) {
            acc[j] += __shfl_xor(acc[j], 1, 64);
            acc[j] = acc[j] * di + b[j];
        }
        float4* ar = (float4*)(agg + (size_t)n * S);
        if (half == 0) {
            #pragma unroll
            for (int c = 0; c < 3; ++c) ar[c] = make_float4(acc[4*c+0], acc[4*c+1], acc[4*c+2], acc[4*c+3]);
        } else {
            #pragma unroll
            for (int c = 3; c < 5; ++c) ar[c] = make_float4(acc[4*c+0], acc[4*c+1], acc[4*c+2], acc[4*c+3]);
        }
        int pr = tid >> 1;
        #pragma unroll
        for (int jo = 0; jo < 10; ++jo) {
            int j = ((jo + pr) % 10) + 10 * half;
            atomicAdd(&ls[j], acc[j]);
            atomicAdd(&ls[DIM + j], acc[j] * acc[j]);
        }
    }
    __syncthreads();
    if (tid < 2 * DIM) atomicAdd(&stats[tid], ls[tid]);
}

__global__ void bn_param_kernel(const float* __restrict__ stats, const float* __restrict__ g,
                                const float* __restrict__ beta, float* __restrict__ ss) {
    int d = threadIdx.x;
    if (d < DIM) {
        float mean = stats[d] * (1.0f / NN);
        float var = stats[DIM + d] * (1.0f / NN) - mean * mean;
        float sc = g[d] * rsqrtf(var + BN_EPS);
        ss[d] = sc;
        ss[DIM + d] = beta[d] - mean * sc;
    }
}

// ---------------- next linear: y = (relu(bn(a)) @ W) * dinv ----------------
template<int S>
__global__ __launch_bounds__(256) void lin_next_kernel(const float* __restrict__ a, const float* __restrict__ ss,
                                                       const float* __restrict__ W, const float* __restrict__ dinv,
                                                       float* __restrict__ out) {
    __shared__ float sW[DIM * DIM];
    __shared__ float sH[64 * 21];
    __shared__ float sS[2 * DIM];
    int tid = threadIdx.x;
    for (int i = tid; i < DIM * DIM; i += 256) sW[i] = W[i];
    if (tid < 2 * DIM) sS[tid] = ss[tid];
    __syncthreads();
    int n0 = blockIdx.x * 64;
    #pragma unroll
    for (int k = 0; k < 5; ++k) {
        int idx = tid + k * 256;
        int row = idx / DIM, colf = idx - row * DIM;
        float v = a[(size_t)(n0 + row) * S + colf];
        sH[row * 21 + colf] = fmaxf(v * sS[colf] + sS[DIM + colf], 0.0f);
    }
    __syncthreads();
    int nl = tid & 63, wq = tid >> 6;
    float acc[5] = {0.f, 0.f, 0.f, 0.f, 0.f};
    for (int f = 0; f < DIM; ++f) {
        float h = sH[nl * 21 + f];
        #pragma unroll
        for (int k = 0; k < 5; ++k) acc[k] += h * sW[f * DIM + wq + 4 * k];
    }
    int n = n0 + nl;
    float dv = dinv[n];
    #pragma unroll
    for (int k = 0; k < 5; ++k) out[(size_t)n * S + wq + 4 * k] = acc[k] * dv;
}

// ---------------- final: relu(bn) -> emb (packed DIM) + segment_max ----------------
template<int S>
__global__ __launch_bounds__(256) void final_kernel(const float* __restrict__ a, const float* __restrict__ ss,
                                                    const int* __restrict__ batch, float* __restrict__ emb,
                                                    unsigned int* __restrict__ ge) {
    __shared__ unsigned int lmax[8 * DIM];
    __shared__ float sS[2 * DIM];
    __shared__ int sg[2];
    int tid = threadIdx.x;
    if (tid < 2 * DIM) sS[tid] = ss[tid];
    int n0 = blockIdx.x * 256;
    if (tid == 0) {
        int nlast = min(n0 + 255, NN - 1);
        sg[0] = batch[n0];
        sg[1] = batch[nlast] - batch[n0] + 1;
    }
    for (int i = tid; i < 8 * DIM; i += 256) lmax[i] = 0u;
    __syncthreads();
    int gmin = sg[0], gspan = sg[1];
    bool uselds = (gspan <= 8);
    int n = n0 + tid;
    if (n < NN) {
        int g = batch[n];
        float vals[DIM];
        const float4* ar = (const float4*)(a + (size_t)n * S);
        float4* er = (float4*)(emb + (size_t)n * DIM);
        #pragma unroll
        for (int c = 0; c < 5; ++c) {
            float4 v = ar[c];
            float r0 = fmaxf(v.x * sS[4*c+0] + sS[DIM + 4*c+0], 0.0f);
            float r1 = fmaxf(v.y * sS[4*c+1] + sS[DIM + 4*c+1], 0.0f);
            float r2 = fmaxf(v.z * sS[4*c+2] + sS[DIM + 4*c+2], 0.0f);
            float r3 = fmaxf(v.w * sS[4*c+3] + sS[DIM + 4*c+3], 0.0f);
            er[c] = make_float4(r0, r1, r2, r3);
            vals[4*c+0] = r0; vals[4*c+1] = r1; vals[4*c+2] = r2; vals[4*c+3] = r3;
        }
        if (uselds) {
            int base = (g - gmin) * DIM;
            #pragma unroll
            for (int jo = 0; jo < DIM; ++jo) {
                int j = (jo + tid) % DIM;
                atomicMax(&lmax[base + j], __float_as_uint(vals[j]));
            }
        } else {
            #pragma unroll
            for (int jo = 0; jo < DIM; ++jo) {
                int j = (jo + tid) % DIM;
                atomicMax(&ge[g * DIM + j], __float_as_uint(vals[j]));
            }
        }
    }
    __syncthreads();
    if (uselds) {
        for (int i = tid; i < gspan * DIM; i += 256) {
            unsigned int v = lmax[i];
            if (v) atomicMax(&ge[gmin * DIM + i], v);
        }
    }
}

// ---------------- fc head ----------------
__global__ __launch_bounds__(256) void fc_kernel(const float* __restrict__ ge, const float* __restrict__ fcW,
                                                 const float* __restrict__ fcb, float* __restrict__ out) {
    int gid = blockIdx.x * 256 + threadIdx.x;
    if (gid >= NGR * NCL) return;
    int g = gid >> 1, c = gid & 1;
    float acc = fcb[c];
    #pragma unroll
    for (int d = 0; d < DIM; ++d) acc += ge[g * DIM + d] * fcW[d * NCL + c];
    out[gid] = acc;
}

template<int S>
static void run_pipeline(const float* x, const int* src, const int* dst, const int* batch,
                         const float* W0, const float* b0, const float* g0, const float* be0,
                         const float* W1, const float* b1, const float* g1, const float* be1,
                         const float* W2, const float* b2, const float* g2, const float* be2,
                         const float* fcW, const float* fcb,
                         float* ws, float* emb, float* ge, float* logits, hipStream_t stream) {
    // ws layout (floats): dinv NN | rowstart NN | stats 192 | ss 120 | ghist NCTR | bbase NCTR+1 | bcur NCTR | pad | bufA NN*S | bufB NN*S | col NE
    float* dinv     = ws;
    int*   rowstart = (int*)(ws + NN);
    float* stats    = ws + 2 * NN;
    float* ss       = stats + 192;
    int*   ghist    = (int*)(ss + 120);
    int*   bbase    = ghist + NCTR;
    int*   bcur     = bbase + NCTR + 1;
    // offset after bcur: 2*NN + 192 + 120 + NCTR + (NCTR+1) + NCTR = 400000 + 9697 = 409697 -> pad to 409700
    float* bufA     = ws + 409700;               // NN*S; aliased as packed[] during CSR build (NN*S >= NE)
    float* bufB     = bufA + (size_t)NN * S;
    int*   col      = (int*)(bufB + (size_t)NN * S);
    unsigned int* packed = (unsigned int*)bufA;

    const int N_BLKS = (NN + 255) / 256;         // 782
    const int G_BLKS = (NN + 127) / 128;         // 1563

    hipMemsetAsync(ghist, 0, NCTR * sizeof(int), stream);
    hipMemsetAsync(stats, 0, 192 * sizeof(float), stream);
    hipMemsetAsync(ge, 0, NGR * DIM * sizeof(float), stream);

    // ---- CSR build: two-level multisplit ----
    hist_kernel<<<NT2, 256, 0, stream>>>(dst, ghist);
    scan_small_kernel<<<1, 1024, 0, stream>>>(ghist, bbase, bcur);
    p2_kernel<<<NT2, 256, 0, stream>>>(src, dst, bcur, packed);
    p3_kernel<<<BKT, 256, 0, stream>>>(packed, bbase, col, rowstart, dinv);

    lin0_kernel<S><<<NN / 64, 256, 0, stream>>>(x, W0, dinv, bufA);   // overwrites packed (dead)

    gather_kernel<S><<<G_BLKS, 256, 0, stream>>>(bufA, col, rowstart, dinv, b0, bufB, stats);
    bn_param_kernel<<<1, 32, 0, stream>>>(stats, g0, be0, ss);
    lin_next_kernel<S><<<NN / 64, 256, 0, stream>>>(bufB, ss, W1, dinv, bufA);

    gather_kernel<S><<<G_BLKS, 256, 0, stream>>>(bufA, col, rowstart, dinv, b1, bufB, stats + 64);
    bn_param_kernel<<<1, 32, 0, stream>>>(stats + 64, g1, be1, ss + 40);
    lin_next_kernel<S><<<NN / 64, 256, 0, stream>>>(bufB, ss + 40, W2, dinv, bufA);

    gather_kernel<S><<<G_BLKS, 256, 0, stream>>>(bufA, col, rowstart, dinv, b2, bufB, stats + 128);
    bn_param_kernel<<<1, 32, 0, stream>>>(stats + 128, g2, be2, ss + 80);

    final_kernel<S><<<N_BLKS, 256, 0, stream>>>(bufB, ss + 80, batch, emb, (unsigned int*)ge);
    fc_kernel<<<(NGR * NCL + 255) / 256, 256, 0, stream>>>(ge, fcW, fcb, logits);
}

extern "C" void kernel_launch(void* const* d_in, const int* in_sizes, int n_in,
                              void* d_out, int out_size, void* d_ws, size_t ws_size,
                              hipStream_t stream) {
    const float* x     = (const float*)d_in[0];
    const int*   ei    = (const int*)d_in[1];
    const int*   src   = ei;
    const int*   dst   = ei + NE;
    const int*   batch = (const int*)d_in[2];
    const float* W0 = (const float*)d_in[3];  const float* b0 = (const float*)d_in[4];
    const float* g0 = (const float*)d_in[5];  const float* be0 = (const float*)d_in[6];
    const float* W1 = (const float*)d_in[7];  const float* b1 = (const float*)d_in[8];
    const float* g1 = (const float*)d_in[9];  const float* be1 = (const float*)d_in[10];
    const float* W2 = (const float*)d_in[11]; const float* b2 = (const float*)d_in[12];
    const float* g2 = (const float*)d_in[13]; const float* be2 = (const float*)d_in[14];
    const float* fcW = (const float*)d_in[15]; const float* fcb = (const float*)d_in[16];

    float* ws     = (float*)d_ws;
    float* emb    = (float*)d_out;               // NN*DIM (packed)
    float* ge     = emb + (size_t)NN * DIM;      // NGR*DIM
    float* logits = ge + NGR * DIM;              // NGR*NCL

    // ws need (floats): 409700 + 2*NN*S + NE
    const size_t need32 = ((size_t)409700 + (size_t)2 * NN * 32 + NE) * 4;
    if (ws_size >= need32) {
        run_pipeline<32>(x, src, dst, batch, W0, b0, g0, be0, W1, b1, g1, be1,
                         W2, b2, g2, be2, fcW, fcb, ws, emb, ge, logits, stream);
    } else {
        run_pipeline<20>(x, src, dst, batch, W0, b0, g0, be0, W1, b1, g1, be1,
                         W2, b2, g2, be2, fcW, fcb, ws, emb, ge, logits, stream);
    }
}

// Round 7
// 496.190 us; speedup vs baseline: 12.7074x; 1.0574x over previous
//
#include <hip/hip_runtime.h>

#define NN 200000
#define NE 4000000
#define FIN 64
#define DIM 20
#define NGR 512
#define NCL 2
#define BN_EPS 1e-5f

#define BKT 391                 // buckets of 512 nodes (dst>>9)
#define BNODE 512
#define NCTR (8 * BKT)
#define T2 32768
#define NT2 ((NE + T2 - 1) / T2)   // 123

typedef unsigned short ushort_t;

__device__ __forceinline__ ushort_t f2bf(float f) {   // RNE bf16
    unsigned u = __float_as_uint(f);
    unsigned r = (u + 0x7fffu + ((u >> 16) & 1u)) >> 16;
    return (ushort_t)r;
}

// add one bf16 row (64B line) into acc[20]
__device__ __forceinline__ void row_add(const ushort_t* __restrict__ yb, int s, float* acc) {
    const uint4* rp = (const uint4*)(yb + (size_t)s * 32);
    uint4 c0 = rp[0], c1 = rp[1];
    uint2 c2 = ((const uint2*)rp)[4];
    unsigned u[10] = {c0.x, c0.y, c0.z, c0.w, c1.x, c1.y, c1.z, c1.w, c2.x, c2.y};
    #pragma unroll
    for (int i = 0; i < 10; ++i) {
        acc[2 * i]     += __uint_as_float(u[i] << 16);
        acc[2 * i + 1] += __uint_as_float(u[i] & 0xffff0000u);
    }
}

// ---------------- pass 1: per-(xcd,bucket) edge histogram ----------------
__global__ __launch_bounds__(256) void hist_kernel(const int* __restrict__ dst, int* __restrict__ ghist) {
    __shared__ int h[BKT];
    int t = threadIdx.x;
    for (int i = t; i < BKT; i += 256) h[i] = 0;
    __syncthreads();
    size_t base = (size_t)blockIdx.x * T2;
    for (int kk = 0; kk < 32; ++kk) {
        size_t e = base + (size_t)kk * 1024 + t * 4;
        if (e + 4 <= NE) {
            int4 d = *(const int4*)(dst + e);
            atomicAdd(&h[d.x >> 9], 1);
            atomicAdd(&h[d.y >> 9], 1);
            atomicAdd(&h[d.z >> 9], 1);
            atomicAdd(&h[d.w >> 9], 1);
        } else {
            for (int j = 0; j < 4; ++j)
                if (e + j < NE) atomicAdd(&h[dst[e + j] >> 9], 1);
        }
    }
    __syncthreads();
    int r = blockIdx.x & 7;
    for (int i = t; i < BKT; i += 256)
        if (h[i]) atomicAdd(&ghist[r * BKT + i], h[i]);
}

// ---------------- pass 2: scan 3128 counters ----------------
__global__ __launch_bounds__(1024) void scan_small_kernel(const int* __restrict__ ghist,
                                                          int* __restrict__ bbase, int* __restrict__ bcur) {
    __shared__ int c[1024];
    int t = threadIdx.x;
    int v[4];
    int sum = 0;
    #pragma unroll
    for (int j = 0; j < 4; ++j) {
        int idx = t * 4 + j;                 // logical order: idx = b*8 + r
        int x = 0;
        if (idx < NCTR) x = ghist[(idx & 7) * BKT + (idx >> 3)];
        v[j] = x; sum += x;
    }
    c[t] = sum;
    __syncthreads();
    for (int off = 1; off < 1024; off <<= 1) {
        int u = (t >= off) ? c[t - off] : 0;
        __syncthreads();
        c[t] += u;
        __syncthreads();
    }
    int run = (t == 0) ? 0 : c[t - 1];
    #pragma unroll
    for (int j = 0; j < 4; ++j) {
        int idx = t * 4 + j;
        if (idx < NCTR) {
            bbase[idx] = run;
            bcur[(idx & 7) * BKT + (idx >> 3)] = run;
        }
        run += v[j];
    }
    if (t == 1023) bbase[NCTR] = run;
}

// ---------------- pass 3: multisplit scatter ----------------
__global__ __launch_bounds__(256) void p2_kernel(const int* __restrict__ src, const int* __restrict__ dst,
                                                 int* __restrict__ bcur, unsigned int* __restrict__ packed) {
    __shared__ int h[BKT], gb[BKT], lc[BKT];
    int t = threadIdx.x;
    for (int i = t; i < BKT; i += 256) { h[i] = 0; lc[i] = 0; }
    __syncthreads();
    size_t base = (size_t)blockIdx.x * T2;
    for (int kk = 0; kk < 32; ++kk) {
        size_t e = base + (size_t)kk * 1024 + t * 4;
        if (e + 4 <= NE) {
            int4 d = *(const int4*)(dst + e);
            atomicAdd(&h[d.x >> 9], 1);
            atomicAdd(&h[d.y >> 9], 1);
            atomicAdd(&h[d.z >> 9], 1);
            atomicAdd(&h[d.w >> 9], 1);
        } else {
            for (int j = 0; j < 4; ++j)
                if (e + j < NE) atomicAdd(&h[dst[e + j] >> 9], 1);
        }
    }
    __syncthreads();
    int r = blockIdx.x & 7;
    for (int i = t; i < BKT; i += 256)
        gb[i] = h[i] ? atomicAdd(&bcur[r * BKT + i], h[i]) : 0;
    __syncthreads();
    for (int kk = 0; kk < 32; ++kk) {
        size_t e = base + (size_t)kk * 1024 + t * 4;
        if (e + 4 <= NE) {
            int4 d = *(const int4*)(dst + e);
            int4 s = *(const int4*)(src + e);
            int b, p;
            b = d.x >> 9; p = gb[b] + atomicAdd(&lc[b], 1); packed[p] = ((unsigned)s.x << 9) | (unsigned)(d.x & 511);
            b = d.y >> 9; p = gb[b] + atomicAdd(&lc[b], 1); packed[p] = ((unsigned)s.y << 9) | (unsigned)(d.y & 511);
            b = d.z >> 9; p = gb[b] + atomicAdd(&lc[b], 1); packed[p] = ((unsigned)s.z << 9) | (unsigned)(d.z & 511);
            b = d.w >> 9; p = gb[b] + atomicAdd(&lc[b], 1); packed[p] = ((unsigned)s.w << 9) | (unsigned)(d.w & 511);
        } else {
            for (int j = 0; j < 4; ++j) {
                if (e + j < NE) {
                    int dd = dst[e + j], ssv = src[e + j];
                    int b = dd >> 9;
                    int p = gb[b] + atomicAdd(&lc[b], 1);
                    packed[p] = ((unsigned)ssv << 9) | (unsigned)(dd & 511);
                }
            }
        }
    }
}

// ---------------- pass 4: per-bucket CSR finalize ----------------
__global__ __launch_bounds__(256) void p3_kernel(const unsigned int* __restrict__ packed, const int* __restrict__ bbase,
                                                 int* __restrict__ col, int* __restrict__ rowstart,
                                                 float* __restrict__ dinv) {
    __shared__ int lcnt[BNODE], lexc[BNODE], lcur[BNODE];
    __shared__ int tmp[256];
    int t = threadIdx.x;
    int b = blockIdx.x;
    for (int i = t; i < BNODE; i += 256) { lcnt[i] = 0; lcur[i] = 0; }
    __syncthreads();
    int beg = bbase[b * 8], end = bbase[(b + 1) * 8];
    for (int i = beg + t; i < end; i += 256) atomicAdd(&lcnt[packed[i] & 511], 1);
    __syncthreads();
    int c2 = lcnt[2 * t] + lcnt[2 * t + 1];
    tmp[t] = c2;
    __syncthreads();
    for (int off = 1; off < 256; off <<= 1) {
        int u = (t >= off) ? tmp[t - off] : 0;
        __syncthreads();
        tmp[t] += u;
        __syncthreads();
    }
    int ex = (t == 0) ? 0 : tmp[t - 1];
    lexc[2 * t] = ex;
    lexc[2 * t + 1] = ex + lcnt[2 * t];
    __syncthreads();
    for (int i = beg + t; i < end; i += 256) {
        unsigned int p = packed[i];
        int ld = p & 511;
        int pos = lexc[ld] + atomicAdd(&lcur[ld], 1);
        col[beg + pos] = (int)(p >> 9);
    }
    int n0 = b * BNODE;
    for (int i = t; i < BNODE; i += 256) {
        int n = n0 + i;
        if (n < NN) {
            int c = lcnt[i];
            rowstart[n] = beg + lexc[i] + c;          // inclusive row end
            dinv[n] = rsqrtf(1.0f + (float)c);
        }
    }
}

// ---------------- layer0 linear: y_bf16 = (x @ W0) * dinv ----------------
__global__ __launch_bounds__(256) void lin0_kernel(const float* __restrict__ x, const float* __restrict__ W,
                                                   const float* __restrict__ dinv, ushort_t* __restrict__ yb) {
    __shared__ float sW[FIN * DIM];
    __shared__ float sX[64 * 65];
    __shared__ ushort_t sO[64 * 32];
    int tid = threadIdx.x;
    for (int i = tid; i < FIN * DIM; i += 256) sW[i] = W[i];
    int n0 = blockIdx.x * 64;
    #pragma unroll
    for (int k = 0; k < 16; ++k) {
        int idx = tid + k * 256;
        int row = idx >> 6, colf = idx & 63;
        sX[row * 65 + colf] = x[(size_t)(n0 + row) * FIN + colf];
    }
    __syncthreads();
    int nl = tid & 63, wq = tid >> 6;
    float acc[5] = {0.f, 0.f, 0.f, 0.f, 0.f};
    for (int f = 0; f < FIN; ++f) {
        float xv = sX[nl * 65 + f];
        #pragma unroll
        for (int k = 0; k < 5; ++k) acc[k] += xv * sW[f * DIM + wq + 4 * k];
    }
    float dv = dinv[n0 + nl];
    #pragma unroll
    for (int k = 0; k < 5; ++k) sO[nl * 32 + wq + 4 * k] = f2bf(acc[k] * dv);
    __syncthreads();
    ((uint4*)(yb + (size_t)n0 * 32))[tid] = ((const uint4*)sO)[tid];   // coalesced 64B rows
}

// ---------------- CSR gather (4 lanes/node) on bf16 rows -> fp32 agg + BN stats ----------------
__global__ __launch_bounds__(256) void gather_kernel(const ushort_t* __restrict__ yb, const int* __restrict__ col,
                                                     const int* __restrict__ rowstart, const float* __restrict__ dinv,
                                                     const float* __restrict__ b, float* __restrict__ agg,
                                                     float* __restrict__ stats) {
    __shared__ float ls[2 * DIM];
    int tid = threadIdx.x;
    if (tid < 2 * DIM) ls[tid] = 0.f;
    __syncthreads();
    int n = blockIdx.x * 64 + (tid >> 2);
    int q = tid & 3;
    float acc[DIM];
    if (n < NN) {
        float di = dinv[n];
        #pragma unroll
        for (int j = 0; j < DIM; ++j) acc[j] = 0.f;
        if (q == 0) row_add(yb, n, acc);       // self-loop
        int beg = (n == 0) ? 0 : rowstart[n - 1];
        int end = rowstart[n];
        for (int e = beg + q; e < end; e += 4) row_add(yb, col[e], acc);
        #pragma unroll
        for (int j = 0; j < DIM; ++j) {
            acc[j] += __shfl_xor(acc[j], 1, 64);
            acc[j] += __shfl_xor(acc[j], 2, 64);
            acc[j] = acc[j] * di + b[j];
        }
        float* ar = agg + (size_t)n * DIM;
        if (q < 3) {
            *(float4*)(ar + 4 * q) = make_float4(acc[4*q], acc[4*q+1], acc[4*q+2], acc[4*q+3]);
        } else {
            *(float4*)(ar + 12) = make_float4(acc[12], acc[13], acc[14], acc[15]);
            *(float4*)(ar + 16) = make_float4(acc[16], acc[17], acc[18], acc[19]);
        }
        int pr = tid >> 2;
        #pragma unroll
        for (int jo = 0; jo < 5; ++jo) {
            int j = 5 * q + ((jo + pr) % 5);
            atomicAdd(&ls[j], acc[j]);
            atomicAdd(&ls[DIM + j], acc[j] * acc[j]);
        }
    }
    __syncthreads();
    if (tid < 2 * DIM) atomicAdd(&stats[tid], ls[tid]);
}

__global__ void bn_param_kernel(const float* __restrict__ stats, const float* __restrict__ g,
                                const float* __restrict__ beta, float* __restrict__ ss) {
    int d = threadIdx.x;
    if (d < DIM) {
        float mean = stats[d] * (1.0f / NN);
        float var = stats[DIM + d] * (1.0f / NN) - mean * mean;
        float sc = g[d] * rsqrtf(var + BN_EPS);
        ss[d] = sc;
        ss[DIM + d] = beta[d] - mean * sc;
    }
}

// ---------------- next linear: y_bf16 = (relu(bn(agg)) @ W) * dinv ----------------
__global__ __launch_bounds__(256) void lin_next_kernel(const float* __restrict__ a, const float* __restrict__ ss,
                                                       const float* __restrict__ W, const float* __restrict__ dinv,
                                                       ushort_t* __restrict__ yb) {
    __shared__ float sW[DIM * DIM];
    __shared__ float sH[64 * 21];
    __shared__ float sS[2 * DIM];
    __shared__ ushort_t sO[64 * 32];
    int tid = threadIdx.x;
    for (int i = tid; i < DIM * DIM; i += 256) sW[i] = W[i];
    if (tid < 2 * DIM) sS[tid] = ss[tid];
    __syncthreads();
    int n0 = blockIdx.x * 64;
    #pragma unroll
    for (int k = 0; k < 5; ++k) {
        int idx = tid + k * 256;
        int row = idx / DIM, colf = idx - row * DIM;
        float v = a[(size_t)(n0 + row) * DIM + colf];
        sH[row * 21 + colf] = fmaxf(v * sS[colf] + sS[DIM + colf], 0.0f);
    }
    __syncthreads();
    int nl = tid & 63, wq = tid >> 6;
    float acc[5] = {0.f, 0.f, 0.f, 0.f, 0.f};
    for (int f = 0; f < DIM; ++f) {
        float h = sH[nl * 21 + f];
        #pragma unroll
        for (int k = 0; k < 5; ++k) acc[k] += h * sW[f * DIM + wq + 4 * k];
    }
    float dv = dinv[n0 + nl];
    #pragma unroll
    for (int k = 0; k < 5; ++k) sO[nl * 32 + wq + 4 * k] = f2bf(acc[k] * dv);
    __syncthreads();
    ((uint4*)(yb + (size_t)n0 * 32))[tid] = ((const uint4*)sO)[tid];
}

// ---------------- final: relu(bn) -> emb + segment_max ----------------
__global__ __launch_bounds__(256) void final_kernel(const float* __restrict__ a, const float* __restrict__ ss,
                                                    const int* __restrict__ batch, float* __restrict__ emb,
                                                    unsigned int* __restrict__ ge) {
    __shared__ unsigned int lmax[8 * DIM];
    __shared__ float sS[2 * DIM];
    __shared__ int sg[2];
    int tid = threadIdx.x;
    if (tid < 2 * DIM) sS[tid] = ss[tid];
    int n0 = blockIdx.x * 256;
    if (tid == 0) {
        int nlast = min(n0 + 255, NN - 1);
        sg[0] = batch[n0];
        sg[1] = batch[nlast] - batch[n0] + 1;
    }
    for (int i = tid; i < 8 * DIM; i += 256) lmax[i] = 0u;
    __syncthreads();
    int gmin = sg[0], gspan = sg[1];
    bool uselds = (gspan <= 8);
    int n = n0 + tid;
    if (n < NN) {
        int g = batch[n];
        float vals[DIM];
        const float4* ar = (const float4*)(a + (size_t)n * DIM);
        float4* er = (float4*)(emb + (size_t)n * DIM);
        #pragma unroll
        for (int c = 0; c < 5; ++c) {
            float4 v = ar[c];
            float r0 = fmaxf(v.x * sS[4*c+0] + sS[DIM + 4*c+0], 0.0f);
            float r1 = fmaxf(v.y * sS[4*c+1] + sS[DIM + 4*c+1], 0.0f);
            float r2 = fmaxf(v.z * sS[4*c+2] + sS[DIM + 4*c+2], 0.0f);
            float r3 = fmaxf(v.w * sS[4*c+3] + sS[DIM + 4*c+3], 0.0f);
            er[c] = make_float4(r0, r1, r2, r3);
            vals[4*c+0] = r0; vals[4*c+1] = r1; vals[4*c+2] = r2; vals[4*c+3] = r3;
        }
        if (uselds) {
            int base = (g - gmin) * DIM;
            #pragma unroll
            for (int jo = 0; jo < DIM; ++jo) {
                int j = (jo + tid) % DIM;
                atomicMax(&lmax[base + j], __float_as_uint(vals[j]));
            }
        } else {
            #pragma unroll
            for (int jo = 0; jo < DIM; ++jo) {
                int j = (jo + tid) % DIM;
                atomicMax(&ge[g * DIM + j], __float_as_uint(vals[j]));
            }
        }
    }
    __syncthreads();
    if (uselds) {
        for (int i = tid; i < gspan * DIM; i += 256) {
            unsigned int v = lmax[i];
            if (v) atomicMax(&ge[gmin * DIM + i], v);
        }
    }
}

// ---------------- fc head ----------------
__global__ __launch_bounds__(256) void fc_kernel(const float* __restrict__ ge, const float* __restrict__ fcW,
                                                 const float* __restrict__ fcb, float* __restrict__ out) {
    int gid = blockIdx.x * 256 + threadIdx.x;
    if (gid >= NGR * NCL) return;
    int g = gid >> 1, c = gid & 1;
    float acc = fcb[c];
    #pragma unroll
    for (int d = 0; d < DIM; ++d) acc += ge[g * DIM + d] * fcW[d * NCL + c];
    out[gid] = acc;
}

extern "C" void kernel_launch(void* const* d_in, const int* in_sizes, int n_in,
                              void* d_out, int out_size, void* d_ws, size_t ws_size,
                              hipStream_t stream) {
    const float* x     = (const float*)d_in[0];
    const int*   ei    = (const int*)d_in[1];
    const int*   src   = ei;
    const int*   dst   = ei + NE;
    const int*   batch = (const int*)d_in[2];
    const float* W0 = (const float*)d_in[3];  const float* b0 = (const float*)d_in[4];
    const float* g0 = (const float*)d_in[5];  const float* be0 = (const float*)d_in[6];
    const float* W1 = (const float*)d_in[7];  const float* b1 = (const float*)d_in[8];
    const float* g1 = (const float*)d_in[9];  const float* be1 = (const float*)d_in[10];
    const float* W2 = (const float*)d_in[11]; const float* b2 = (const float*)d_in[12];
    const float* g2 = (const float*)d_in[13]; const float* be2 = (const float*)d_in[14];
    const float* fcW = (const float*)d_in[15]; const float* fcb = (const float*)d_in[16];

    float* ws = (float*)d_ws;
    // layout (floats): dinv NN | rowstart NN | stats 192 | ss 120 | ghist NCTR | bbase NCTR+1 | bcur NCTR | pad
    float* dinv     = ws;
    int*   rowstart = (int*)(ws + NN);
    float* stats    = ws + 2 * NN;
    float* ss       = stats + 192;
    int*   ghist    = (int*)(ss + 120);
    int*   bbase    = ghist + NCTR;
    int*   bcur     = bbase + NCTR + 1;
    float* agg      = ws + 409700;                      // NN*DIM fp32 == 4,000,000 floats; aliases packed[]
    unsigned int* packed = (unsigned int*)agg;          // NE u32 == NN*DIM
    ushort_t* ybuf  = (ushort_t*)(ws + 4409712);        // NN*32 bf16 (64B-aligned rows)
    int*   col      = (int*)(ws + 4409712 + (size_t)NN * 16);   // NE ints

    float* emb    = (float*)d_out;                      // NN*DIM
    float* ge     = emb + (size_t)NN * DIM;             // NGR*DIM
    float* logits = ge + NGR * DIM;                     // NGR*NCL

    const int N_BLKS = (NN + 255) / 256;                // 782
    const int L_BLKS = NN / 64;                         // 3125 (lin + gather)

    hipMemsetAsync(ghist, 0, NCTR * sizeof(int), stream);
    hipMemsetAsync(stats, 0, 192 * sizeof(float), stream);
    hipMemsetAsync(ge, 0, NGR * DIM * sizeof(float), stream);

    // ---- CSR build: two-level multisplit (topology shared by all 3 layers) ----
    hist_kernel<<<NT2, 256, 0, stream>>>(dst, ghist);
    scan_small_kernel<<<1, 1024, 0, stream>>>(ghist, bbase, bcur);
    p2_kernel<<<NT2, 256, 0, stream>>>(src, dst, bcur, packed);
    p3_kernel<<<BKT, 256, 0, stream>>>(packed, bbase, col, rowstart, dinv);

    lin0_kernel<<<L_BLKS, 256, 0, stream>>>(x, W0, dinv, ybuf);   // packed dead after p3

    gather_kernel<<<L_BLKS, 256, 0, stream>>>(ybuf, col, rowstart, dinv, b0, agg, stats);
    bn_param_kernel<<<1, 32, 0, stream>>>(stats, g0, be0, ss);
    lin_next_kernel<<<L_BLKS, 256, 0, stream>>>(agg, ss, W1, dinv, ybuf);

    gather_kernel<<<L_BLKS, 256, 0, stream>>>(ybuf, col, rowstart, dinv, b1, agg, stats + 64);
    bn_param_kernel<<<1, 32, 0, stream>>>(stats + 64, g1, be1, ss + 40);
    lin_next_kernel<<<L_BLKS, 256, 0, stream>>>(agg, ss + 40, W2, dinv, ybuf);

    gather_kernel<<<L_BLKS, 256, 0, stream>>>(ybuf, col, rowstart, dinv, b2, agg, stats + 128);
    bn_param_kernel<<<1, 32, 0, stream>>>(stats + 128, g2, be2, ss + 80);

    final_kernel<<<N_BLKS, 256, 0, stream>>>(agg, ss + 80, batch, emb, (unsigned int*)ge);
    fc_kernel<<<(NGR * NCL + 255) / 256, 256, 0, stream>>>(ge, fcW, fcb, logits);
}

// Round 8
// 460.198 us; speedup vs baseline: 13.7012x; 1.0782x over previous
//
#include <hip/hip_runtime.h>

#define NN 200000
#define NE 4000000
#define FIN 64
#define DIM 20
#define NGR 512
#define NCL 2
#define BN_EPS 1e-5f

#define BKT 391                 // buckets of 512 nodes (dst>>9)
#define BNODE 512
#define NCTR (8 * BKT)
#define T2 32768
#define NT2 ((NE + T2 - 1) / T2)   // 123
#define NSLC 8
#define SLCW 25000              // src-slice width (1.5625 MB bf16 rows per slice)

typedef unsigned short ushort_t;

__device__ __forceinline__ ushort_t f2bf(float f) {   // RNE bf16
    unsigned u = __float_as_uint(f);
    unsigned r = (u + 0x7fffu + ((u >> 16) & 1u)) >> 16;
    return (ushort_t)r;
}

// add one bf16 row (first 40B of a 64B line) into acc[20]
__device__ __forceinline__ void row_add(const ushort_t* __restrict__ yb, int s, float* acc) {
    const uint4* rp = (const uint4*)(yb + (size_t)s * 32);
    uint4 c0 = rp[0], c1 = rp[1];
    uint2 c2 = ((const uint2*)rp)[4];
    unsigned u[10] = {c0.x, c0.y, c0.z, c0.w, c1.x, c1.y, c1.z, c1.w, c2.x, c2.y};
    #pragma unroll
    for (int i = 0; i < 10; ++i) {
        acc[2 * i]     += __uint_as_float(u[i] << 16);
        acc[2 * i + 1] += __uint_as_float(u[i] & 0xffff0000u);
    }
}

// ---------------- pass 1: per-(xcd,bucket) edge histogram ----------------
__global__ __launch_bounds__(256) void hist_kernel(const int* __restrict__ dst, int* __restrict__ ghist) {
    __shared__ int h[BKT];
    int t = threadIdx.x;
    for (int i = t; i < BKT; i += 256) h[i] = 0;
    __syncthreads();
    size_t base = (size_t)blockIdx.x * T2;
    for (int kk = 0; kk < 32; ++kk) {
        size_t e = base + (size_t)kk * 1024 + t * 4;
        if (e + 4 <= NE) {
            int4 d = *(const int4*)(dst + e);
            atomicAdd(&h[d.x >> 9], 1);
            atomicAdd(&h[d.y >> 9], 1);
            atomicAdd(&h[d.z >> 9], 1);
            atomicAdd(&h[d.w >> 9], 1);
        } else {
            for (int j = 0; j < 4; ++j)
                if (e + j < NE) atomicAdd(&h[dst[e + j] >> 9], 1);
        }
    }
    __syncthreads();
    int r = blockIdx.x & 7;
    for (int i = t; i < BKT; i += 256)
        if (h[i]) atomicAdd(&ghist[r * BKT + i], h[i]);
}

// ---------------- pass 2: scan 3128 counters ----------------
__global__ __launch_bounds__(1024) void scan_small_kernel(const int* __restrict__ ghist,
                                                          int* __restrict__ bbase, int* __restrict__ bcur) {
    __shared__ int c[1024];
    int t = threadIdx.x;
    int v[4];
    int sum = 0;
    #pragma unroll
    for (int j = 0; j < 4; ++j) {
        int idx = t * 4 + j;                 // logical order: idx = b*8 + r
        int x = 0;
        if (idx < NCTR) x = ghist[(idx & 7) * BKT + (idx >> 3)];
        v[j] = x; sum += x;
    }
    c[t] = sum;
    __syncthreads();
    for (int off = 1; off < 1024; off <<= 1) {
        int u = (t >= off) ? c[t - off] : 0;
        __syncthreads();
        c[t] += u;
        __syncthreads();
    }
    int run = (t == 0) ? 0 : c[t - 1];
    #pragma unroll
    for (int j = 0; j < 4; ++j) {
        int idx = t * 4 + j;
        if (idx < NCTR) {
            bbase[idx] = run;
            bcur[(idx & 7) * BKT + (idx >> 3)] = run;
        }
        run += v[j];
    }
    if (t == 1023) bbase[NCTR] = run;
}

// ---------------- pass 3: multisplit scatter ----------------
__global__ __launch_bounds__(256) void p2_kernel(const int* __restrict__ src, const int* __restrict__ dst,
                                                 int* __restrict__ bcur, unsigned int* __restrict__ packed) {
    __shared__ int h[BKT], gb[BKT], lc[BKT];
    int t = threadIdx.x;
    for (int i = t; i < BKT; i += 256) { h[i] = 0; lc[i] = 0; }
    __syncthreads();
    size_t base = (size_t)blockIdx.x * T2;
    for (int kk = 0; kk < 32; ++kk) {
        size_t e = base + (size_t)kk * 1024 + t * 4;
        if (e + 4 <= NE) {
            int4 d = *(const int4*)(dst + e);
            atomicAdd(&h[d.x >> 9], 1);
            atomicAdd(&h[d.y >> 9], 1);
            atomicAdd(&h[d.z >> 9], 1);
            atomicAdd(&h[d.w >> 9], 1);
        } else {
            for (int j = 0; j < 4; ++j)
                if (e + j < NE) atomicAdd(&h[dst[e + j] >> 9], 1);
        }
    }
    __syncthreads();
    int r = blockIdx.x & 7;
    for (int i = t; i < BKT; i += 256)
        gb[i] = h[i] ? atomicAdd(&bcur[r * BKT + i], h[i]) : 0;
    __syncthreads();
    for (int kk = 0; kk < 32; ++kk) {
        size_t e = base + (size_t)kk * 1024 + t * 4;
        if (e + 4 <= NE) {
            int4 d = *(const int4*)(dst + e);
            int4 s = *(const int4*)(src + e);
            int b, p;
            b = d.x >> 9; p = gb[b] + atomicAdd(&lc[b], 1); packed[p] = ((unsigned)s.x << 9) | (unsigned)(d.x & 511);
            b = d.y >> 9; p = gb[b] + atomicAdd(&lc[b], 1); packed[p] = ((unsigned)s.y << 9) | (unsigned)(d.y & 511);
            b = d.z >> 9; p = gb[b] + atomicAdd(&lc[b], 1); packed[p] = ((unsigned)s.z << 9) | (unsigned)(d.z & 511);
            b = d.w >> 9; p = gb[b] + atomicAdd(&lc[b], 1); packed[p] = ((unsigned)s.w << 9) | (unsigned)(d.w & 511);
        } else {
            for (int j = 0; j < 4; ++j) {
                if (e + j < NE) {
                    int dd = dst[e + j], ssv = src[e + j];
                    int b = dd >> 9;
                    int p = gb[b] + atomicAdd(&lc[b], 1);
                    packed[p] = ((unsigned)ssv << 9) | (unsigned)(dd & 511);
                }
            }
        }
    }
}

// ---------------- pass 4: per-bucket CSR finalize, keyed (dst_low, src_slice) ----------------
// Also writes per-(node,slice) u16 counts into the 64B y-row tail (bytes 48..63).
__global__ __launch_bounds__(256) void p3_kernel(const unsigned int* __restrict__ packed, const int* __restrict__ bbase,
                                                 int* __restrict__ col, int* __restrict__ rowstart,
                                                 float* __restrict__ dinv, ushort_t* __restrict__ yb) {
    __shared__ int lcnt[BNODE * NSLC], lexc[BNODE * NSLC], lcur[BNODE * NSLC];
    __shared__ int tmp[256];
    int t = threadIdx.x;
    int b = blockIdx.x;
    for (int i = t; i < BNODE * NSLC; i += 256) { lcnt[i] = 0; lcur[i] = 0; }
    __syncthreads();
    int beg = bbase[b * 8], end = bbase[(b + 1) * 8];
    for (int i = beg + t; i < end; i += 256) {
        unsigned p = packed[i];
        int k = (int)(p & 511) * NSLC + (int)(p >> 9) / SLCW;
        atomicAdd(&lcnt[k], 1);
    }
    __syncthreads();
    int myv[16];
    int ssum = 0;
    #pragma unroll
    for (int j = 0; j < 16; ++j) { myv[j] = lcnt[t * 16 + j]; ssum += myv[j]; }
    tmp[t] = ssum;
    __syncthreads();
    for (int off = 1; off < 256; off <<= 1) {
        int u = (t >= off) ? tmp[t - off] : 0;
        __syncthreads();
        tmp[t] += u;
        __syncthreads();
    }
    int run = (t == 0) ? 0 : tmp[t - 1];
    #pragma unroll
    for (int j = 0; j < 16; ++j) { lexc[t * 16 + j] = run; run += myv[j]; }
    __syncthreads();
    for (int i = beg + t; i < end; i += 256) {
        unsigned p = packed[i];
        int sv = (int)(p >> 9);
        int k = (int)(p & 511) * NSLC + sv / SLCW;
        int pos = lexc[k] + atomicAdd(&lcur[k], 1);
        col[beg + pos] = sv;
    }
    __syncthreads();
    int n0 = b * BNODE;
    for (int i = t; i < BNODE; i += 256) {
        int n = n0 + i;
        if (n < NN) {
            int st = lexc[i * NSLC];
            int en = (i == BNODE - 1) ? (end - beg) : lexc[(i + 1) * NSLC];
            rowstart[n] = beg + en;                       // inclusive row end
            dinv[n] = rsqrtf(1.0f + (float)(en - st));
            unsigned c01 = (unsigned)lcnt[i*NSLC+0] | ((unsigned)lcnt[i*NSLC+1] << 16);
            unsigned c23 = (unsigned)lcnt[i*NSLC+2] | ((unsigned)lcnt[i*NSLC+3] << 16);
            unsigned c45 = (unsigned)lcnt[i*NSLC+4] | ((unsigned)lcnt[i*NSLC+5] << 16);
            unsigned c67 = (unsigned)lcnt[i*NSLC+6] | ((unsigned)lcnt[i*NSLC+7] << 16);
            *(uint4*)(yb + (size_t)n * 32 + 24) = make_uint4(c01, c23, c45, c67);
        }
    }
}

// ---------------- layer0 linear: y_bf16 = (x @ W0) * dinv  (writes 48B/row, preserves tail) ----------------
__global__ __launch_bounds__(256) void lin0_kernel(const float* __restrict__ x, const float* __restrict__ W,
                                                   const float* __restrict__ dinv, ushort_t* __restrict__ yb) {
    __shared__ float sW[FIN * DIM];
    __shared__ float sX[64 * 65];
    __shared__ ushort_t sO[64 * 32];
    int tid = threadIdx.x;
    for (int i = tid; i < FIN * DIM; i += 256) sW[i] = W[i];
    int n0 = blockIdx.x * 64;
    #pragma unroll
    for (int k = 0; k < 16; ++k) {
        int idx = tid + k * 256;
        int row = idx >> 6, colf = idx & 63;
        sX[row * 65 + colf] = x[(size_t)(n0 + row) * FIN + colf];
    }
    __syncthreads();
    int nl = tid & 63, wq = tid >> 6;
    float acc[5] = {0.f, 0.f, 0.f, 0.f, 0.f};
    for (int f = 0; f < FIN; ++f) {
        float xv = sX[nl * 65 + f];
        #pragma unroll
        for (int k = 0; k < 5; ++k) acc[k] += xv * sW[f * DIM + wq + 4 * k];
    }
    float dv = dinv[n0 + nl];
    #pragma unroll
    for (int k = 0; k < 5; ++k) sO[nl * 32 + wq + 4 * k] = f2bf(acc[k] * dv);
    __syncthreads();
    if (tid < 192) {                                   // 64 rows x 3 uint4 (bytes 0..47)
        int row = tid / 3, part = tid - row * 3;
        ((uint4*)(yb + (size_t)(n0 + row) * 32))[part] = ((const uint4*)(sO + row * 32))[part];
    }
}

// ---------------- CSR gather, slice-major (L2-phased), 2 lanes/node, reg accumulators ----------------
__global__ __launch_bounds__(256) void gather_kernel(const ushort_t* __restrict__ yb, const int* __restrict__ col,
                                                     const int* __restrict__ rowstart, const float* __restrict__ dinv,
                                                     const float* __restrict__ b, float* __restrict__ agg,
                                                     float* __restrict__ stats) {
    __shared__ float ls[2 * DIM];
    int tid = threadIdx.x;
    if (tid < 2 * DIM) ls[tid] = 0.f;
    __syncthreads();
    int n = blockIdx.x * 128 + (tid >> 1);
    int h = tid & 1;
    float acc[DIM];
    if (n < NN) {
        float di = dinv[n];
        #pragma unroll
        for (int j = 0; j < DIM; ++j) acc[j] = 0.f;
        uint4 cv = *(const uint4*)(yb + (size_t)n * 32 + 24);   // per-slice counts (row tail)
        if (h == 0) row_add(yb, n, acc);                        // self-loop
        int off = (n == 0) ? 0 : rowstart[n - 1];
        unsigned cw[4] = {cv.x, cv.y, cv.z, cv.w};
        #pragma unroll
        for (int s = 0; s < NSLC; ++s) {                        // slice-major: waves sweep slices in phase
            int cs = (int)((cw[s >> 1] >> ((s & 1) * 16)) & 0xffffu);
            for (int e = off + h; e < off + cs; e += 2) row_add(yb, col[e], acc);
            off += cs;
        }
        #pragma unroll
        for (int j = 0; j < DIM; ++j) {
            acc[j] += __shfl_xor(acc[j], 1, 64);
            acc[j] = acc[j] * di + b[j];
        }
        float* ar = agg + (size_t)n * DIM;
        if (h == 0) {
            *(float4*)(ar)     = make_float4(acc[0], acc[1], acc[2], acc[3]);
            *(float4*)(ar + 4) = make_float4(acc[4], acc[5], acc[6], acc[7]);
            *(float4*)(ar + 8) = make_float4(acc[8], acc[9], acc[10], acc[11]);
        } else {
            *(float4*)(ar + 12) = make_float4(acc[12], acc[13], acc[14], acc[15]);
            *(float4*)(ar + 16) = make_float4(acc[16], acc[17], acc[18], acc[19]);
        }
        int pr = tid >> 1;
        #pragma unroll
        for (int jo = 0; jo < 10; ++jo) {
            int j = ((jo + pr) % 10) + 10 * h;
            atomicAdd(&ls[j], acc[j]);
            atomicAdd(&ls[DIM + j], acc[j] * acc[j]);
        }
    }
    __syncthreads();
    if (tid < 2 * DIM) atomicAdd(&stats[tid], ls[tid]);
}

__global__ void bn_param_kernel(const float* __restrict__ stats, const float* __restrict__ g,
                                const float* __restrict__ beta, float* __restrict__ ss) {
    int d = threadIdx.x;
    if (d < DIM) {
        float mean = stats[d] * (1.0f / NN);
        float var = stats[DIM + d] * (1.0f / NN) - mean * mean;
        float sc = g[d] * rsqrtf(var + BN_EPS);
        ss[d] = sc;
        ss[DIM + d] = beta[d] - mean * sc;
    }
}

// ---------------- next linear: y_bf16 = (relu(bn(agg)) @ W) * dinv  (48B/row stores) ----------------
__global__ __launch_bounds__(256) void lin_next_kernel(const float* __restrict__ a, const float* __restrict__ ss,
                                                       const float* __restrict__ W, const float* __restrict__ dinv,
                                                       ushort_t* __restrict__ yb) {
    __shared__ float sW[DIM * DIM];
    __shared__ float sH[64 * 21];
    __shared__ float sS[2 * DIM];
    __shared__ ushort_t sO[64 * 32];
    int tid = threadIdx.x;
    for (int i = tid; i < DIM * DIM; i += 256) sW[i] = W[i];
    if (tid < 2 * DIM) sS[tid] = ss[tid];
    __syncthreads();
    int n0 = blockIdx.x * 64;
    #pragma unroll
    for (int k = 0; k < 5; ++k) {
        int idx = tid + k * 256;
        int row = idx / DIM, colf = idx - row * DIM;
        float v = a[(size_t)(n0 + row) * DIM + colf];
        sH[row * 21 + colf] = fmaxf(v * sS[colf] + sS[DIM + colf], 0.0f);
    }
    __syncthreads();
    int nl = tid & 63, wq = tid >> 6;
    float acc[5] = {0.f, 0.f, 0.f, 0.f, 0.f};
    for (int f = 0; f < DIM; ++f) {
        float h = sH[nl * 21 + f];
        #pragma unroll
        for (int k = 0; k < 5; ++k) acc[k] += h * sW[f * DIM + wq + 4 * k];
    }
    float dv = dinv[n0 + nl];
    #pragma unroll
    for (int k = 0; k < 5; ++k) sO[nl * 32 + wq + 4 * k] = f2bf(acc[k] * dv);
    __syncthreads();
    if (tid < 192) {
        int row = tid / 3, part = tid - row * 3;
        ((uint4*)(yb + (size_t)(n0 + row) * 32))[part] = ((const uint4*)(sO + row * 32))[part];
    }
}

// ---------------- final: relu(bn) -> emb + segment_max ----------------
__global__ __launch_bounds__(256) void final_kernel(const float* __restrict__ a, const float* __restrict__ ss,
                                                    const int* __restrict__ batch, float* __restrict__ emb,
                                                    unsigned int* __restrict__ ge) {
    __shared__ unsigned int lmax[8 * DIM];
    __shared__ float sS[2 * DIM];
    __shared__ int sg[2];
    int tid = threadIdx.x;
    if (tid < 2 * DIM) sS[tid] = ss[tid];
    int n0 = blockIdx.x * 256;
    if (tid == 0) {
        int nlast = min(n0 + 255, NN - 1);
        sg[0] = batch[n0];
        sg[1] = batch[nlast] - batch[n0] + 1;
    }
    for (int i = tid; i < 8 * DIM; i += 256) lmax[i] = 0u;
    __syncthreads();
    int gmin = sg[0], gspan = sg[1];
    bool uselds = (gspan <= 8);
    int n = n0 + tid;
    if (n < NN) {
        int g = batch[n];
        float vals[DIM];
        const float4* ar = (const float4*)(a + (size_t)n * DIM);
        float4* er = (float4*)(emb + (size_t)n * DIM);
        #pragma unroll
        for (int c = 0; c < 5; ++c) {
            float4 v = ar[c];
            float r0 = fmaxf(v.x * sS[4*c+0] + sS[DIM + 4*c+0], 0.0f);
            float r1 = fmaxf(v.y * sS[4*c+1] + sS[DIM + 4*c+1], 0.0f);
            float r2 = fmaxf(v.z * sS[4*c+2] + sS[DIM + 4*c+2], 0.0f);
            float r3 = fmaxf(v.w * sS[4*c+3] + sS[DIM + 4*c+3], 0.0f);
            er[c] = make_float4(r0, r1, r2, r3);
            vals[4*c+0] = r0; vals[4*c+1] = r1; vals[4*c+2] = r2; vals[4*c+3] = r3;
        }
        if (uselds) {
            int base = (g - gmin) * DIM;
            #pragma unroll
            for (int jo = 0; jo < DIM; ++jo) {
                int j = (jo + tid) % DIM;
                atomicMax(&lmax[base + j], __float_as_uint(vals[j]));
            }
        } else {
            #pragma unroll
            for (int jo = 0; jo < DIM; ++jo) {
                int j = (jo + tid) % DIM;
                atomicMax(&ge[g * DIM + j], __float_as_uint(vals[j]));
            }
        }
    }
    __syncthreads();
    if (uselds) {
        for (int i = tid; i < gspan * DIM; i += 256) {
            unsigned int v = lmax[i];
            if (v) atomicMax(&ge[gmin * DIM + i], v);
        }
    }
}

// ---------------- fc head ----------------
__global__ __launch_bounds__(256) void fc_kernel(const float* __restrict__ ge, const float* __restrict__ fcW,
                                                 const float* __restrict__ fcb, float* __restrict__ out) {
    int gid = blockIdx.x * 256 + threadIdx.x;
    if (gid >= NGR * NCL) return;
    int g = gid >> 1, c = gid & 1;
    float acc = fcb[c];
    #pragma unroll
    for (int d = 0; d < DIM; ++d) acc += ge[g * DIM + d] * fcW[d * NCL + c];
    out[gid] = acc;
}

extern "C" void kernel_launch(void* const* d_in, const int* in_sizes, int n_in,
                              void* d_out, int out_size, void* d_ws, size_t ws_size,
                              hipStream_t stream) {
    const float* x     = (const float*)d_in[0];
    const int*   ei    = (const int*)d_in[1];
    const int*   src   = ei;
    const int*   dst   = ei + NE;
    const int*   batch = (const int*)d_in[2];
    const float* W0 = (const float*)d_in[3];  const float* b0 = (const float*)d_in[4];
    const float* g0 = (const float*)d_in[5];  const float* be0 = (const float*)d_in[6];
    const float* W1 = (const float*)d_in[7];  const float* b1 = (const float*)d_in[8];
    const float* g1 = (const float*)d_in[9];  const float* be1 = (const float*)d_in[10];
    const float* W2 = (const float*)d_in[11]; const float* b2 = (const float*)d_in[12];
    const float* g2 = (const float*)d_in[13]; const float* be2 = (const float*)d_in[14];
    const float* fcW = (const float*)d_in[15]; const float* fcb = (const float*)d_in[16];

    float* ws = (float*)d_ws;
    float* dinv     = ws;                               // NN
    int*   rowstart = (int*)(ws + NN);                  // NN
    float* stats    = ws + 2 * NN;                      // 192
    float* ss       = stats + 192;                      // 120
    int*   ghist    = (int*)(ss + 120);                 // NCTR
    int*   bbase    = ghist + NCTR;                     // NCTR+1
    int*   bcur     = bbase + NCTR + 1;                 // NCTR
    float* agg      = ws + 409700;                      // NN*DIM fp32; aliases packed[]
    unsigned int* packed = (unsigned int*)agg;          // NE u32 == NN*DIM
    ushort_t* ybuf  = (ushort_t*)(ws + 4409712);        // NN rows x 64B (40B data + 8B pad + 16B cnt16)
    int*   col      = (int*)(ws + 4409712 + (size_t)NN * 16);   // NE ints

    float* emb    = (float*)d_out;                      // NN*DIM
    float* ge     = emb + (size_t)NN * DIM;             // NGR*DIM
    float* logits = ge + NGR * DIM;                     // NGR*NCL

    const int N_BLKS = (NN + 255) / 256;                // 782
    const int L_BLKS = NN / 64;                         // 3125 (linears)
    const int G_BLKS = (NN + 127) / 128;                // 1563 (gather, ~fully resident)

    hipMemsetAsync(ghist, 0, NCTR * sizeof(int), stream);
    hipMemsetAsync(stats, 0, 192 * sizeof(float), stream);
    hipMemsetAsync(ge, 0, NGR * DIM * sizeof(float), stream);

    // ---- CSR build: two-level multisplit, (dst_low, src_slice)-sorted segments ----
    hist_kernel<<<NT2, 256, 0, stream>>>(dst, ghist);
    scan_small_kernel<<<1, 1024, 0, stream>>>(ghist, bbase, bcur);
    p2_kernel<<<NT2, 256, 0, stream>>>(src, dst, bcur, packed);
    p3_kernel<<<BKT, 256, 0, stream>>>(packed, bbase, col, rowstart, dinv, ybuf);

    lin0_kernel<<<L_BLKS, 256, 0, stream>>>(x, W0, dinv, ybuf);   // packed dead after p3

    gather_kernel<<<G_BLKS, 256, 0, stream>>>(ybuf, col, rowstart, dinv, b0, agg, stats);
    bn_param_kernel<<<1, 32, 0, stream>>>(stats, g0, be0, ss);
    lin_next_kernel<<<L_BLKS, 256, 0, stream>>>(agg, ss, W1, dinv, ybuf);

    gather_kernel<<<G_BLKS, 256, 0, stream>>>(ybuf, col, rowstart, dinv, b1, agg, stats + 64);
    bn_param_kernel<<<1, 32, 0, stream>>>(stats + 64, g1, be1, ss + 40);
    lin_next_kernel<<<L_BLKS, 256, 0, stream>>>(agg, ss + 40, W2, dinv, ybuf);

    gather_kernel<<<G_BLKS, 256, 0, stream>>>(ybuf, col, rowstart, dinv, b2, agg, stats + 128);
    bn_param_kernel<<<1, 32, 0, stream>>>(stats + 128, g2, be2, ss + 80);

    final_kernel<<<N_BLKS, 256, 0, stream>>>(agg, ss + 80, batch, emb, (unsigned int*)ge);
    fc_kernel<<<(NGR * NCL + 255) / 256, 256, 0, stream>>>(ge, fcW, fcb, logits);
}

// Round 9
// 437.677 us; speedup vs baseline: 14.4062x; 1.0515x over previous
//
#include <hip/hip_runtime.h>

#define NN 200000
#define NE 4000000
#define FIN 64
#define DIM 20
#define NGR 512
#define NCL 2
#define BN_EPS 1e-5f

#define BKT 391                 // buckets of 512 nodes (dst>>9)
#define BNODE 512
#define NCTR (8 * BKT)
#define T2 32768
#define NT2 ((NE + T2 - 1) / T2)   // 123
#define NSLC 8
#define SLCW 25000              // src-slice width (1.5625 MB bf16 rows per slice)

typedef unsigned short ushort_t;

__device__ __forceinline__ ushort_t f2bf(float f) {   // RNE bf16
    unsigned u = __float_as_uint(f);
    unsigned r = (u + 0x7fffu + ((u >> 16) & 1u)) >> 16;
    return (ushort_t)r;
}

struct Row { uint4 a, b; uint2 c; };

__device__ __forceinline__ Row row_load(const ushort_t* __restrict__ yb, int s) {
    const uint4* rp = (const uint4*)(yb + (size_t)s * 32);
    Row r;
    r.a = rp[0];
    r.b = rp[1];
    r.c = ((const uint2*)rp)[4];
    return r;
}

__device__ __forceinline__ void row_acc(const Row& r, float* acc) {
    unsigned u[10] = {r.a.x, r.a.y, r.a.z, r.a.w, r.b.x, r.b.y, r.b.z, r.b.w, r.c.x, r.c.y};
    #pragma unroll
    for (int i = 0; i < 10; ++i) {
        acc[2 * i]     += __uint_as_float(u[i] << 16);
        acc[2 * i + 1] += __uint_as_float(u[i] & 0xffff0000u);
    }
}

// ---------------- pass 1: per-(xcd,bucket) edge histogram ----------------
__global__ __launch_bounds__(256) void hist_kernel(const int* __restrict__ dst, int* __restrict__ ghist) {
    __shared__ int h[BKT];
    int t = threadIdx.x;
    for (int i = t; i < BKT; i += 256) h[i] = 0;
    __syncthreads();
    size_t base = (size_t)blockIdx.x * T2;
    for (int kk = 0; kk < 32; ++kk) {
        size_t e = base + (size_t)kk * 1024 + t * 4;
        if (e + 4 <= NE) {
            int4 d = *(const int4*)(dst + e);
            atomicAdd(&h[d.x >> 9], 1);
            atomicAdd(&h[d.y >> 9], 1);
            atomicAdd(&h[d.z >> 9], 1);
            atomicAdd(&h[d.w >> 9], 1);
        } else {
            for (int j = 0; j < 4; ++j)
                if (e + j < NE) atomicAdd(&h[dst[e + j] >> 9], 1);
        }
    }
    __syncthreads();
    int r = blockIdx.x & 7;
    for (int i = t; i < BKT; i += 256)
        if (h[i]) atomicAdd(&ghist[r * BKT + i], h[i]);
}

// ---------------- pass 2: scan 3128 counters ----------------
__global__ __launch_bounds__(1024) void scan_small_kernel(const int* __restrict__ ghist,
                                                          int* __restrict__ bbase, int* __restrict__ bcur) {
    __shared__ int c[1024];
    int t = threadIdx.x;
    int v[4];
    int sum = 0;
    #pragma unroll
    for (int j = 0; j < 4; ++j) {
        int idx = t * 4 + j;                 // logical order: idx = b*8 + r
        int x = 0;
        if (idx < NCTR) x = ghist[(idx & 7) * BKT + (idx >> 3)];
        v[j] = x; sum += x;
    }
    c[t] = sum;
    __syncthreads();
    for (int off = 1; off < 1024; off <<= 1) {
        int u = (t >= off) ? c[t - off] : 0;
        __syncthreads();
        c[t] += u;
        __syncthreads();
    }
    int run = (t == 0) ? 0 : c[t - 1];
    #pragma unroll
    for (int j = 0; j < 4; ++j) {
        int idx = t * 4 + j;
        if (idx < NCTR) {
            bbase[idx] = run;
            bcur[(idx & 7) * BKT + (idx >> 3)] = run;
        }
        run += v[j];
    }
    if (t == 1023) bbase[NCTR] = run;
}

// ---------------- pass 3: multisplit scatter ----------------
__global__ __launch_bounds__(256) void p2_kernel(const int* __restrict__ src, const int* __restrict__ dst,
                                                 int* __restrict__ bcur, unsigned int* __restrict__ packed) {
    __shared__ int h[BKT], gb[BKT], lc[BKT];
    int t = threadIdx.x;
    for (int i = t; i < BKT; i += 256) { h[i] = 0; lc[i] = 0; }
    __syncthreads();
    size_t base = (size_t)blockIdx.x * T2;
    for (int kk = 0; kk < 32; ++kk) {
        size_t e = base + (size_t)kk * 1024 + t * 4;
        if (e + 4 <= NE) {
            int4 d = *(const int4*)(dst + e);
            atomicAdd(&h[d.x >> 9], 1);
            atomicAdd(&h[d.y >> 9], 1);
            atomicAdd(&h[d.z >> 9], 1);
            atomicAdd(&h[d.w >> 9], 1);
        } else {
            for (int j = 0; j < 4; ++j)
                if (e + j < NE) atomicAdd(&h[dst[e + j] >> 9], 1);
        }
    }
    __syncthreads();
    int r = blockIdx.x & 7;
    for (int i = t; i < BKT; i += 256)
        gb[i] = h[i] ? atomicAdd(&bcur[r * BKT + i], h[i]) : 0;
    __syncthreads();
    for (int kk = 0; kk < 32; ++kk) {
        size_t e = base + (size_t)kk * 1024 + t * 4;
        if (e + 4 <= NE) {
            int4 d = *(const int4*)(dst + e);
            int4 s = *(const int4*)(src + e);
            int b, p;
            b = d.x >> 9; p = gb[b] + atomicAdd(&lc[b], 1); packed[p] = ((unsigned)s.x << 9) | (unsigned)(d.x & 511);
            b = d.y >> 9; p = gb[b] + atomicAdd(&lc[b], 1); packed[p] = ((unsigned)s.y << 9) | (unsigned)(d.y & 511);
            b = d.z >> 9; p = gb[b] + atomicAdd(&lc[b], 1); packed[p] = ((unsigned)s.z << 9) | (unsigned)(d.z & 511);
            b = d.w >> 9; p = gb[b] + atomicAdd(&lc[b], 1); packed[p] = ((unsigned)s.w << 9) | (unsigned)(d.w & 511);
        } else {
            for (int j = 0; j < 4; ++j) {
                if (e + j < NE) {
                    int dd = dst[e + j], ssv = src[e + j];
                    int b = dd >> 9;
                    int p = gb[b] + atomicAdd(&lc[b], 1);
                    packed[p] = ((unsigned)ssv << 9) | (unsigned)(dd & 511);
                }
            }
        }
    }
}

// ---------------- pass 4: per-bucket CSR finalize, segments ordered by (dst_low, src_slice) ----------------
__global__ __launch_bounds__(256) void p3_kernel(const unsigned int* __restrict__ packed, const int* __restrict__ bbase,
                                                 int* __restrict__ col, int* __restrict__ rowstart,
                                                 float* __restrict__ dinv) {
    __shared__ int lcnt[BNODE * NSLC], lexc[BNODE * NSLC], lcur[BNODE * NSLC];
    __shared__ int tmp[256];
    int t = threadIdx.x;
    int b = blockIdx.x;
    for (int i = t; i < BNODE * NSLC; i += 256) { lcnt[i] = 0; lcur[i] = 0; }
    __syncthreads();
    int beg = bbase[b * 8], end = bbase[(b + 1) * 8];
    for (int i = beg + t; i < end; i += 256) {
        unsigned p = packed[i];
        int k = (int)(p & 511) * NSLC + (int)(p >> 9) / SLCW;
        atomicAdd(&lcnt[k], 1);
    }
    __syncthreads();
    int myv[16];
    int ssum = 0;
    #pragma unroll
    for (int j = 0; j < 16; ++j) { myv[j] = lcnt[t * 16 + j]; ssum += myv[j]; }
    tmp[t] = ssum;
    __syncthreads();
    for (int off = 1; off < 256; off <<= 1) {
        int u = (t >= off) ? tmp[t - off] : 0;
        __syncthreads();
        tmp[t] += u;
        __syncthreads();
    }
    int run = (t == 0) ? 0 : tmp[t - 1];
    #pragma unroll
    for (int j = 0; j < 16; ++j) { lexc[t * 16 + j] = run; run += myv[j]; }
    __syncthreads();
    for (int i = beg + t; i < end; i += 256) {
        unsigned p = packed[i];
        int sv = (int)(p >> 9);
        int k = (int)(p & 511) * NSLC + sv / SLCW;
        int pos = lexc[k] + atomicAdd(&lcur[k], 1);
        col[beg + pos] = sv;
    }
    __syncthreads();
    int n0 = b * BNODE;
    for (int i = t; i < BNODE; i += 256) {
        int n = n0 + i;
        if (n < NN) {
            int st = lexc[i * NSLC];
            int en = (i == BNODE - 1) ? (end - beg) : lexc[(i + 1) * NSLC];
            rowstart[n] = beg + en;                       // inclusive row end
            dinv[n] = rsqrtf(1.0f + (float)(en - st));
        }
    }
}

// ---------------- layer0 linear: y_bf16 = (x @ W0) * dinv ----------------
__global__ __launch_bounds__(256) void lin0_kernel(const float* __restrict__ x, const float* __restrict__ W,
                                                   const float* __restrict__ dinv, ushort_t* __restrict__ yb) {
    __shared__ float sW[FIN * DIM];
    __shared__ float sX[64 * 65];
    __shared__ ushort_t sO[64 * 32];
    int tid = threadIdx.x;
    for (int i = tid; i < FIN * DIM; i += 256) sW[i] = W[i];
    int n0 = blockIdx.x * 64;
    #pragma unroll
    for (int k = 0; k < 16; ++k) {
        int idx = tid + k * 256;
        int row = idx >> 6, colf = idx & 63;
        sX[row * 65 + colf] = x[(size_t)(n0 + row) * FIN + colf];
    }
    __syncthreads();
    int nl = tid & 63, wq = tid >> 6;
    float acc[5] = {0.f, 0.f, 0.f, 0.f, 0.f};
    for (int f = 0; f < FIN; ++f) {
        float xv = sX[nl * 65 + f];
        #pragma unroll
        for (int k = 0; k < 5; ++k) acc[k] += xv * sW[f * DIM + wq + 4 * k];
    }
    float dv = dinv[n0 + nl];
    #pragma unroll
    for (int k = 0; k < 5; ++k) sO[nl * 32 + wq + 4 * k] = f2bf(acc[k] * dv);
    __syncthreads();
    if (tid < 192) {                                   // 64 rows x 3 uint4 (bytes 0..47)
        int row = tid / 3, part = tid - row * 3;
        ((uint4*)(yb + (size_t)(n0 + row) * 32))[part] = ((const uint4*)(sO + row * 32))[part];
    }
}

// ---------------- CSR gather: 2 lanes/node, 4-edge software pipeline (MLP), reg accumulators ----------------
__global__ __launch_bounds__(256) void gather_kernel(const ushort_t* __restrict__ yb, const int* __restrict__ col,
                                                     const int* __restrict__ rowstart, const float* __restrict__ dinv,
                                                     const float* __restrict__ b, float* __restrict__ agg,
                                                     float* __restrict__ stats) {
    __shared__ float ls[2 * DIM];
    int tid = threadIdx.x;
    if (tid < 2 * DIM) ls[tid] = 0.f;
    __syncthreads();
    int n = blockIdx.x * 128 + (tid >> 1);
    int h = tid & 1;
    float acc[DIM];
    if (n < NN) {
        float di = dinv[n];
        #pragma unroll
        for (int j = 0; j < DIM; ++j) acc[j] = 0.f;
        if (h == 0) row_acc(row_load(yb, n), acc);               // self-loop
        int beg = (n == 0) ? 0 : rowstart[n - 1];
        int end = rowstart[n];
        int e = beg + h;
        int cnt = (end - e + 1) >> 1;                            // this lane's edge count
        while (cnt >= 4) {                                       // 4 rows in flight
            int s0 = col[e], s1 = col[e + 2], s2 = col[e + 4], s3 = col[e + 6];
            Row r0 = row_load(yb, s0);
            Row r1 = row_load(yb, s1);
            Row r2 = row_load(yb, s2);
            Row r3 = row_load(yb, s3);
            row_acc(r0, acc);
            row_acc(r1, acc);
            row_acc(r2, acc);
            row_acc(r3, acc);
            e += 8; cnt -= 4;
        }
        if (cnt >= 2) {                                          // 2 in flight
            int s0 = col[e], s1 = col[e + 2];
            Row r0 = row_load(yb, s0);
            Row r1 = row_load(yb, s1);
            row_acc(r0, acc);
            row_acc(r1, acc);
            e += 4; cnt -= 2;
        }
        if (cnt > 0) row_acc(row_load(yb, col[e]), acc);
        #pragma unroll
        for (int j = 0; j < DIM; ++j) {
            acc[j] += __shfl_xor(acc[j], 1, 64);
            acc[j] = acc[j] * di + b[j];
        }
        float* ar = agg + (size_t)n * DIM;
        if (h == 0) {
            *(float4*)(ar)     = make_float4(acc[0], acc[1], acc[2], acc[3]);
            *(float4*)(ar + 4) = make_float4(acc[4], acc[5], acc[6], acc[7]);
            *(float4*)(ar + 8) = make_float4(acc[8], acc[9], acc[10], acc[11]);
        } else {
            *(float4*)(ar + 12) = make_float4(acc[12], acc[13], acc[14], acc[15]);
            *(float4*)(ar + 16) = make_float4(acc[16], acc[17], acc[18], acc[19]);
        }
        int pr = tid >> 1;
        #pragma unroll
        for (int jo = 0; jo < 10; ++jo) {
            int j = ((jo + pr) % 10) + 10 * h;
            atomicAdd(&ls[j], acc[j]);
            atomicAdd(&ls[DIM + j], acc[j] * acc[j]);
        }
    }
    __syncthreads();
    if (tid < 2 * DIM) atomicAdd(&stats[tid], ls[tid]);
}

__global__ void bn_param_kernel(const float* __restrict__ stats, const float* __restrict__ g,
                                const float* __restrict__ beta, float* __restrict__ ss) {
    int d = threadIdx.x;
    if (d < DIM) {
        float mean = stats[d] * (1.0f / NN);
        float var = stats[DIM + d] * (1.0f / NN) - mean * mean;
        float sc = g[d] * rsqrtf(var + BN_EPS);
        ss[d] = sc;
        ss[DIM + d] = beta[d] - mean * sc;
    }
}

// ---------------- next linear: y_bf16 = (relu(bn(agg)) @ W) * dinv ----------------
__global__ __launch_bounds__(256) void lin_next_kernel(const float* __restrict__ a, const float* __restrict__ ss,
                                                       const float* __restrict__ W, const float* __restrict__ dinv,
                                                       ushort_t* __restrict__ yb) {
    __shared__ float sW[DIM * DIM];
    __shared__ float sH[64 * 21];
    __shared__ float sS[2 * DIM];
    __shared__ ushort_t sO[64 * 32];
    int tid = threadIdx.x;
    for (int i = tid; i < DIM * DIM; i += 256) sW[i] = W[i];
    if (tid < 2 * DIM) sS[tid] = ss[tid];
    __syncthreads();
    int n0 = blockIdx.x * 64;
    #pragma unroll
    for (int k = 0; k < 5; ++k) {
        int idx = tid + k * 256;
        int row = idx / DIM, colf = idx - row * DIM;
        float v = a[(size_t)(n0 + row) * DIM + colf];
        sH[row * 21 + colf] = fmaxf(v * sS[colf] + sS[DIM + colf], 0.0f);
    }
    __syncthreads();
    int nl = tid & 63, wq = tid >> 6;
    float acc[5] = {0.f, 0.f, 0.f, 0.f, 0.f};
    for (int f = 0; f < DIM; ++f) {
        float h = sH[nl * 21 + f];
        #pragma unroll
        for (int k = 0; k < 5; ++k) acc[k] += h * sW[f * DIM + wq + 4 * k];
    }
    float dv = dinv[n0 + nl];
    #pragma unroll
    for (int k = 0; k < 5; ++k) sO[nl * 32 + wq + 4 * k] = f2bf(acc[k] * dv);
    __syncthreads();
    if (tid < 192) {
        int row = tid / 3, part = tid - row * 3;
        ((uint4*)(yb + (size_t)(n0 + row) * 32))[part] = ((const uint4*)(sO + row * 32))[part];
    }
}

// ---------------- final: relu(bn) -> emb + segment_max ----------------
__global__ __launch_bounds__(256) void final_kernel(const float* __restrict__ a, const float* __restrict__ ss,
                                                    const int* __restrict__ batch, float* __restrict__ emb,
                                                    unsigned int* __restrict__ ge) {
    __shared__ unsigned int lmax[8 * DIM];
    __shared__ float sS[2 * DIM];
    __shared__ int sg[2];
    int tid = threadIdx.x;
    if (tid < 2 * DIM) sS[tid] = ss[tid];
    int n0 = blockIdx.x * 256;
    if (tid == 0) {
        int nlast = min(n0 + 255, NN - 1);
        sg[0] = batch[n0];
        sg[1] = batch[nlast] - batch[n0] + 1;
    }
    for (int i = tid; i < 8 * DIM; i += 256) lmax[i] = 0u;
    __syncthreads();
    int gmin = sg[0], gspan = sg[1];
    bool uselds = (gspan <= 8);
    int n = n0 + tid;
    if (n < NN) {
        int g = batch[n];
        float vals[DIM];
        const float4* ar = (const float4*)(a + (size_t)n * DIM);
        float4* er = (float4*)(emb + (size_t)n * DIM);
        #pragma unroll
        for (int c = 0; c < 5; ++c) {
            float4 v = ar[c];
            float r0 = fmaxf(v.x * sS[4*c+0] + sS[DIM + 4*c+0], 0.0f);
            float r1 = fmaxf(v.y * sS[4*c+1] + sS[DIM + 4*c+1], 0.0f);
            float r2 = fmaxf(v.z * sS[4*c+2] + sS[DIM + 4*c+2], 0.0f);
            float r3 = fmaxf(v.w * sS[4*c+3] + sS[DIM + 4*c+3], 0.0f);
            er[c] = make_float4(r0, r1, r2, r3);
            vals[4*c+0] = r0; vals[4*c+1] = r1; vals[4*c+2] = r2; vals[4*c+3] = r3;
        }
        if (uselds) {
            int base = (g - gmin) * DIM;
            #pragma unroll
            for (int jo = 0; jo < DIM; ++jo) {
                int j = (jo + tid) % DIM;
                atomicMax(&lmax[base + j], __float_as_uint(vals[j]));
            }
        } else {
            #pragma unroll
            for (int jo = 0; jo < DIM; ++jo) {
                int j = (jo + tid) % DIM;
                atomicMax(&ge[g * DIM + j], __float_as_uint(vals[j]));
            }
        }
    }
    __syncthreads();
    if (uselds) {
        for (int i = tid; i < gspan * DIM; i += 256) {
            unsigned int v = lmax[i];
            if (v) atomicMax(&ge[gmin * DIM + i], v);
        }
    }
}

// ---------------- fc head ----------------
__global__ __launch_bounds__(256) void fc_kernel(const float* __restrict__ ge, const float* __restrict__ fcW,
                                                 const float* __restrict__ fcb, float* __restrict__ out) {
    int gid = blockIdx.x * 256 + threadIdx.x;
    if (gid >= NGR * NCL) return;
    int g = gid >> 1, c = gid & 1;
    float acc = fcb[c];
    #pragma unroll
    for (int d = 0; d < DIM; ++d) acc += ge[g * DIM + d] * fcW[d * NCL + c];
    out[gid] = acc;
}

extern "C" void kernel_launch(void* const* d_in, const int* in_sizes, int n_in,
                              void* d_out, int out_size, void* d_ws, size_t ws_size,
                              hipStream_t stream) {
    const float* x     = (const float*)d_in[0];
    const int*   ei    = (const int*)d_in[1];
    const int*   src   = ei;
    const int*   dst   = ei + NE;
    const int*   batch = (const int*)d_in[2];
    const float* W0 = (const float*)d_in[3];  const float* b0 = (const float*)d_in[4];
    const float* g0 = (const float*)d_in[5];  const float* be0 = (const float*)d_in[6];
    const float* W1 = (const float*)d_in[7];  const float* b1 = (const float*)d_in[8];
    const float* g1 = (const float*)d_in[9];  const float* be1 = (const float*)d_in[10];
    const float* W2 = (const float*)d_in[11]; const float* b2 = (const float*)d_in[12];
    const float* g2 = (const float*)d_in[13]; const float* be2 = (const float*)d_in[14];
    const float* fcW = (const float*)d_in[15]; const float* fcb = (const float*)d_in[16];

    float* ws = (float*)d_ws;
    float* dinv     = ws;                               // NN
    int*   rowstart = (int*)(ws + NN);                  // NN
    float* stats    = ws + 2 * NN;                      // 192
    float* ss       = stats + 192;                      // 120
    int*   ghist    = (int*)(ss + 120);                 // NCTR
    int*   bbase    = ghist + NCTR;                     // NCTR+1
    int*   bcur     = bbase + NCTR + 1;                 // NCTR
    float* agg      = ws + 409700;                      // NN*DIM fp32; aliases packed[]
    unsigned int* packed = (unsigned int*)agg;          // NE u32 == NN*DIM
    ushort_t* ybuf  = (ushort_t*)(ws + 4409712);        // NN rows x 64B (40B data + 24B pad)
    int*   col      = (int*)(ws + 4409712 + (size_t)NN * 16);   // NE ints

    float* emb    = (float*)d_out;                      // NN*DIM
    float* ge     = emb + (size_t)NN * DIM;             // NGR*DIM
    float* logits = ge + NGR * DIM;                     // NGR*NCL

    const int N_BLKS = (NN + 255) / 256;                // 782
    const int L_BLKS = NN / 64;                         // 3125 (linears)
    const int G_BLKS = (NN + 127) / 128;                // 1563 (gather)

    hipMemsetAsync(ghist, 0, NCTR * sizeof(int), stream);
    hipMemsetAsync(stats, 0, 192 * sizeof(float), stream);
    hipMemsetAsync(ge, 0, NGR * DIM * sizeof(float), stream);

    // ---- CSR build: two-level multisplit, (dst_low, src_slice)-sorted segments ----
    hist_kernel<<<NT2, 256, 0, stream>>>(dst, ghist);
    scan_small_kernel<<<1, 1024, 0, stream>>>(ghist, bbase, bcur);
    p2_kernel<<<NT2, 256, 0, stream>>>(src, dst, bcur, packed);
    p3_kernel<<<BKT, 256, 0, stream>>>(packed, bbase, col, rowstart, dinv);

    lin0_kernel<<<L_BLKS, 256, 0, stream>>>(x, W0, dinv, ybuf);   // packed dead after p3

    gather_kernel<<<G_BLKS, 256, 0, stream>>>(ybuf, col, rowstart, dinv, b0, agg, stats);
    bn_param_kernel<<<1, 32, 0, stream>>>(stats, g0, be0, ss);
    lin_next_kernel<<<L_BLKS, 256, 0, stream>>>(agg, ss, W1, dinv, ybuf);

    gather_kernel<<<G_BLKS, 256, 0, stream>>>(ybuf, col, rowstart, dinv, b1, agg, stats + 64);
    bn_param_kernel<<<1, 32, 0, stream>>>(stats + 64, g1, be1, ss + 40);
    lin_next_kernel<<<L_BLKS, 256, 0, stream>>>(agg, ss + 40, W2, dinv, ybuf);

    gather_kernel<<<G_BLKS, 256, 0, stream>>>(ybuf, col, rowstart, dinv, b2, agg, stats + 128);
    bn_param_kernel<<<1, 32, 0, stream>>>(stats + 128, g2, be2, ss + 80);

    final_kernel<<<N_BLKS, 256, 0, stream>>>(agg, ss + 80, batch, emb, (unsigned int*)ge);
    fc_kernel<<<(NGR * NCL + 255) / 256, 256, 0, stream>>>(ge, fcW, fcb, logits);
}

// Round 10
// 430.577 us; speedup vs baseline: 14.6438x; 1.0165x over previous
//
#include <hip/hip_runtime.h>

#define NN 200000
#define NE 4000000
#define FIN 64
#define DIM 20
#define NGR 512
#define NCL 2
#define BN_EPS 1e-5f

#define BKT 391                 // buckets of 512 nodes (dst>>9)
#define BNODE 512
#define NCTR (8 * BKT)
#define T2 32768
#define NT2 ((NE + T2 - 1) / T2)   // 123
#define NSLC 4
#define SLCW 50000              // src-slice width (3.2 MB bf16 rows per slice)

typedef unsigned short ushort_t;

__device__ __forceinline__ ushort_t f2bf(float f) {   // RNE bf16
    unsigned u = __float_as_uint(f);
    unsigned r = (u + 0x7fffu + ((u >> 16) & 1u)) >> 16;
    return (ushort_t)r;
}

struct Row { uint4 a, b; uint2 c; };

__device__ __forceinline__ Row row_load(const ushort_t* __restrict__ yb, int s) {
    const uint4* rp = (const uint4*)(yb + (size_t)s * 32);
    Row r;
    r.a = rp[0];
    r.b = rp[1];
    r.c = ((const uint2*)rp)[4];
    return r;
}

__device__ __forceinline__ void row_acc(const Row& r, float* acc) {
    unsigned u[10] = {r.a.x, r.a.y, r.a.z, r.a.w, r.b.x, r.b.y, r.b.z, r.b.w, r.c.x, r.c.y};
    #pragma unroll
    for (int i = 0; i < 10; ++i) {
        acc[2 * i]     += __uint_as_float(u[i] << 16);
        acc[2 * i + 1] += __uint_as_float(u[i] & 0xffff0000u);
    }
}

// ---------------- pass 1: per-(xcd,bucket) edge histogram ----------------
__global__ __launch_bounds__(256) void hist_kernel(const int* __restrict__ dst, int* __restrict__ ghist) {
    __shared__ int h[BKT];
    int t = threadIdx.x;
    for (int i = t; i < BKT; i += 256) h[i] = 0;
    __syncthreads();
    size_t base = (size_t)blockIdx.x * T2;
    for (int kk = 0; kk < 32; ++kk) {
        size_t e = base + (size_t)kk * 1024 + t * 4;
        if (e + 4 <= NE) {
            int4 d = *(const int4*)(dst + e);
            atomicAdd(&h[d.x >> 9], 1);
            atomicAdd(&h[d.y >> 9], 1);
            atomicAdd(&h[d.z >> 9], 1);
            atomicAdd(&h[d.w >> 9], 1);
        } else {
            for (int j = 0; j < 4; ++j)
                if (e + j < NE) atomicAdd(&h[dst[e + j] >> 9], 1);
        }
    }
    __syncthreads();
    int r = blockIdx.x & 7;
    for (int i = t; i < BKT; i += 256)
        if (h[i]) atomicAdd(&ghist[r * BKT + i], h[i]);
}

// ---------------- pass 2: scan 3128 counters ----------------
__global__ __launch_bounds__(1024) void scan_small_kernel(const int* __restrict__ ghist,
                                                          int* __restrict__ bbase, int* __restrict__ bcur) {
    __shared__ int c[1024];
    int t = threadIdx.x;
    int v[4];
    int sum = 0;
    #pragma unroll
    for (int j = 0; j < 4; ++j) {
        int idx = t * 4 + j;                 // logical order: idx = b*8 + r
        int x = 0;
        if (idx < NCTR) x = ghist[(idx & 7) * BKT + (idx >> 3)];
        v[j] = x; sum += x;
    }
    c[t] = sum;
    __syncthreads();
    for (int off = 1; off < 1024; off <<= 1) {
        int u = (t >= off) ? c[t - off] : 0;
        __syncthreads();
        c[t] += u;
        __syncthreads();
    }
    int run = (t == 0) ? 0 : c[t - 1];
    #pragma unroll
    for (int j = 0; j < 4; ++j) {
        int idx = t * 4 + j;
        if (idx < NCTR) {
            bbase[idx] = run;
            bcur[(idx & 7) * BKT + (idx >> 3)] = run;
        }
        run += v[j];
    }
    if (t == 1023) bbase[NCTR] = run;
}

// ---------------- pass 3: multisplit scatter ----------------
__global__ __launch_bounds__(256) void p2_kernel(const int* __restrict__ src, const int* __restrict__ dst,
                                                 int* __restrict__ bcur, unsigned int* __restrict__ packed) {
    __shared__ int h[BKT], gb[BKT], lc[BKT];
    int t = threadIdx.x;
    for (int i = t; i < BKT; i += 256) { h[i] = 0; lc[i] = 0; }
    __syncthreads();
    size_t base = (size_t)blockIdx.x * T2;
    for (int kk = 0; kk < 32; ++kk) {
        size_t e = base + (size_t)kk * 1024 + t * 4;
        if (e + 4 <= NE) {
            int4 d = *(const int4*)(dst + e);
            atomicAdd(&h[d.x >> 9], 1);
            atomicAdd(&h[d.y >> 9], 1);
            atomicAdd(&h[d.z >> 9], 1);
            atomicAdd(&h[d.w >> 9], 1);
        } else {
            for (int j = 0; j < 4; ++j)
                if (e + j < NE) atomicAdd(&h[dst[e + j] >> 9], 1);
        }
    }
    __syncthreads();
    int r = blockIdx.x & 7;
    for (int i = t; i < BKT; i += 256)
        gb[i] = h[i] ? atomicAdd(&bcur[r * BKT + i], h[i]) : 0;
    __syncthreads();
    for (int kk = 0; kk < 32; ++kk) {
        size_t e = base + (size_t)kk * 1024 + t * 4;
        if (e + 4 <= NE) {
            int4 d = *(const int4*)(dst + e);
            int4 s = *(const int4*)(src + e);
            int b, p;
            b = d.x >> 9; p = gb[b] + atomicAdd(&lc[b], 1); packed[p] = ((unsigned)s.x << 9) | (unsigned)(d.x & 511);
            b = d.y >> 9; p = gb[b] + atomicAdd(&lc[b], 1); packed[p] = ((unsigned)s.y << 9) | (unsigned)(d.y & 511);
            b = d.z >> 9; p = gb[b] + atomicAdd(&lc[b], 1); packed[p] = ((unsigned)s.z << 9) | (unsigned)(d.z & 511);
            b = d.w >> 9; p = gb[b] + atomicAdd(&lc[b], 1); packed[p] = ((unsigned)s.w << 9) | (unsigned)(d.w & 511);
        } else {
            for (int j = 0; j < 4; ++j) {
                if (e + j < NE) {
                    int dd = dst[e + j], ssv = src[e + j];
                    int b = dd >> 9;
                    int p = gb[b] + atomicAdd(&lc[b], 1);
                    packed[p] = ((unsigned)ssv << 9) | (unsigned)(dd & 511);
                }
            }
        }
    }
}

// ---------------- pass 4: per-bucket CSR finalize, segments ordered by (dst_low, src_slice) ----------------
__global__ __launch_bounds__(256) void p3_kernel(const unsigned int* __restrict__ packed, const int* __restrict__ bbase,
                                                 int* __restrict__ col, int* __restrict__ rowstart,
                                                 float* __restrict__ dinv) {
    __shared__ int lcnt[BNODE * NSLC], lexc[BNODE * NSLC], lcur[BNODE * NSLC];
    __shared__ int tmp[256];
    int t = threadIdx.x;
    int b = blockIdx.x;
    for (int i = t; i < BNODE * NSLC; i += 256) { lcnt[i] = 0; lcur[i] = 0; }
    __syncthreads();
    int beg = bbase[b * 8], end = bbase[(b + 1) * 8];
    for (int i = beg + t; i < end; i += 256) {
        unsigned p = packed[i];
        int k = (int)(p & 511) * NSLC + (int)(p >> 9) / SLCW;
        atomicAdd(&lcnt[k], 1);
    }
    __syncthreads();
    int myv[8];
    int ssum = 0;
    #pragma unroll
    for (int j = 0; j < 8; ++j) { myv[j] = lcnt[t * 8 + j]; ssum += myv[j]; }
    tmp[t] = ssum;
    __syncthreads();
    for (int off = 1; off < 256; off <<= 1) {
        int u = (t >= off) ? tmp[t - off] : 0;
        __syncthreads();
        tmp[t] += u;
        __syncthreads();
    }
    int run = (t == 0) ? 0 : tmp[t - 1];
    #pragma unroll
    for (int j = 0; j < 8; ++j) { lexc[t * 8 + j] = run; run += myv[j]; }
    __syncthreads();
    for (int i = beg + t; i < end; i += 256) {
        unsigned p = packed[i];
        int sv = (int)(p >> 9);
        int k = (int)(p & 511) * NSLC + sv / SLCW;
        int pos = lexc[k] + atomicAdd(&lcur[k], 1);
        col[beg + pos] = sv;
    }
    __syncthreads();
    int n0 = b * BNODE;
    for (int i = t; i < BNODE; i += 256) {
        int n = n0 + i;
        if (n < NN) {
            int st = lexc[i * NSLC];
            int en = (i == BNODE - 1) ? (end - beg) : lexc[(i + 1) * NSLC];
            rowstart[n] = beg + en;                       // inclusive row end
            dinv[n] = rsqrtf(1.0f + (float)(en - st));
        }
    }
}

// ---------------- layer0 linear: y_bf16 = (x @ W0) * dinv ----------------
__global__ __launch_bounds__(256) void lin0_kernel(const float* __restrict__ x, const float* __restrict__ W,
                                                   const float* __restrict__ dinv, ushort_t* __restrict__ yb) {
    __shared__ float sW[FIN * DIM];
    __shared__ float sX[64 * 65];
    __shared__ ushort_t sO[64 * 32];
    int tid = threadIdx.x;
    for (int i = tid; i < FIN * DIM; i += 256) sW[i] = W[i];
    int n0 = blockIdx.x * 64;
    #pragma unroll
    for (int k = 0; k < 16; ++k) {
        int idx = tid + k * 256;
        int row = idx >> 6, colf = idx & 63;
        sX[row * 65 + colf] = x[(size_t)(n0 + row) * FIN + colf];
    }
    __syncthreads();
    int nl = tid & 63, wq = tid >> 6;
    float acc[5] = {0.f, 0.f, 0.f, 0.f, 0.f};
    for (int f = 0; f < FIN; ++f) {
        float xv = sX[nl * 65 + f];
        #pragma unroll
        for (int k = 0; k < 5; ++k) acc[k] += xv * sW[f * DIM + wq + 4 * k];
    }
    float dv = dinv[n0 + nl];
    #pragma unroll
    for (int k = 0; k < 5; ++k) sO[nl * 32 + wq + 4 * k] = f2bf(acc[k] * dv);
    __syncthreads();
    if (tid < 192) {                                   // 64 rows x 3 uint4 (bytes 0..47)
        int row = tid / 3, part = tid - row * 3;
        ((uint4*)(yb + (size_t)(n0 + row) * 32))[part] = ((const uint4*)(sO + row * 32))[part];
    }
}

// ---------------- CSR gather: 2 lanes/node, 4-edge pinned software pipeline, reg accumulators ----------------
__global__ __launch_bounds__(256) void gather_kernel(const ushort_t* __restrict__ yb, const int* __restrict__ col,
                                                     const int* __restrict__ rowstart, const float* __restrict__ dinv,
                                                     const float* __restrict__ b, float* __restrict__ agg,
                                                     float* __restrict__ stats) {
    __shared__ float ls[2 * DIM];
    int tid = threadIdx.x;
    if (tid < 2 * DIM) ls[tid] = 0.f;
    __syncthreads();
    int n = blockIdx.x * 128 + (tid >> 1);
    int h = tid & 1;
    float acc[DIM];
    if (n < NN) {
        float di = dinv[n];
        #pragma unroll
        for (int j = 0; j < DIM; ++j) acc[j] = 0.f;
        if (h == 0) row_acc(row_load(yb, n), acc);               // self-loop
        int beg = (n == 0) ? 0 : rowstart[n - 1];
        int end = rowstart[n];
        int e = beg + h;
        int cnt = (end - e + 1) >> 1;                            // this lane's edge count
        while (cnt >= 4) {                                       // 4 rows truly in flight
            int s0 = col[e], s1 = col[e + 2], s2 = col[e + 4], s3 = col[e + 6];
            Row r0 = row_load(yb, s0);
            Row r1 = row_load(yb, s1);
            Row r2 = row_load(yb, s2);
            Row r3 = row_load(yb, s3);
            __builtin_amdgcn_sched_barrier(0);                   // pin: no acc hoisted above loads
            row_acc(r0, acc);
            row_acc(r1, acc);
            row_acc(r2, acc);
            row_acc(r3, acc);
            e += 8; cnt -= 4;
        }
        if (cnt >= 2) {                                          // 2 in flight
            int s0 = col[e], s1 = col[e + 2];
            Row r0 = row_load(yb, s0);
            Row r1 = row_load(yb, s1);
            __builtin_amdgcn_sched_barrier(0);
            row_acc(r0, acc);
            row_acc(r1, acc);
            e += 4; cnt -= 2;
        }
        if (cnt > 0) row_acc(row_load(yb, col[e]), acc);
        #pragma unroll
        for (int j = 0; j < DIM; ++j) {
            acc[j] += __shfl_xor(acc[j], 1, 64);
            acc[j] = acc[j] * di + b[j];
        }
        float* ar = agg + (size_t)n * DIM;
        if (h == 0) {
            *(float4*)(ar)     = make_float4(acc[0], acc[1], acc[2], acc[3]);
            *(float4*)(ar + 4) = make_float4(acc[4], acc[5], acc[6], acc[7]);
            *(float4*)(ar + 8) = make_float4(acc[8], acc[9], acc[10], acc[11]);
        } else {
            *(float4*)(ar + 12) = make_float4(acc[12], acc[13], acc[14], acc[15]);
            *(float4*)(ar + 16) = make_float4(acc[16], acc[17], acc[18], acc[19]);
        }
        int pr = tid >> 1;
        #pragma unroll
        for (int jo = 0; jo < 10; ++jo) {
            int j = ((jo + pr) % 10) + 10 * h;
            atomicAdd(&ls[j], acc[j]);
            atomicAdd(&ls[DIM + j], acc[j] * acc[j]);
        }
    }
    __syncthreads();
    if (tid < 2 * DIM) atomicAdd(&stats[tid], ls[tid]);
}

__global__ void bn_param_kernel(const float* __restrict__ stats, const float* __restrict__ g,
                                const float* __restrict__ beta, float* __restrict__ ss) {
    int d = threadIdx.x;
    if (d < DIM) {
        float mean = stats[d] * (1.0f / NN);
        float var = stats[DIM + d] * (1.0f / NN) - mean * mean;
        float sc = g[d] * rsqrtf(var + BN_EPS);
        ss[d] = sc;
        ss[DIM + d] = beta[d] - mean * sc;
    }
}

// ---------------- next linear: y_bf16 = (relu(bn(agg)) @ W) * dinv ----------------
__global__ __launch_bounds__(256) void lin_next_kernel(const float* __restrict__ a, const float* __restrict__ ss,
                                                       const float* __restrict__ W, const float* __restrict__ dinv,
                                                       ushort_t* __restrict__ yb) {
    __shared__ float sW[DIM * DIM];
    __shared__ float sH[64 * 21];
    __shared__ float sS[2 * DIM];
    __shared__ ushort_t sO[64 * 32];
    int tid = threadIdx.x;
    for (int i = tid; i < DIM * DIM; i += 256) sW[i] = W[i];
    if (tid < 2 * DIM) sS[tid] = ss[tid];
    __syncthreads();
    int n0 = blockIdx.x * 64;
    #pragma unroll
    for (int k = 0; k < 5; ++k) {
        int idx = tid + k * 256;
        int row = idx / DIM, colf = idx - row * DIM;
        float v = a[(size_t)(n0 + row) * DIM + colf];
        sH[row * 21 + colf] = fmaxf(v * sS[colf] + sS[DIM + colf], 0.0f);
    }
    __syncthreads();
    int nl = tid & 63, wq = tid >> 6;
    float acc[5] = {0.f, 0.f, 0.f, 0.f, 0.f};
    for (int f = 0; f < DIM; ++f) {
        float h = sH[nl * 21 + f];
        #pragma unroll
        for (int k = 0; k < 5; ++k) acc[k] += h * sW[f * DIM + wq + 4 * k];
    }
    float dv = dinv[n0 + nl];
    #pragma unroll
    for (int k = 0; k < 5; ++k) sO[nl * 32 + wq + 4 * k] = f2bf(acc[k] * dv);
    __syncthreads();
    if (tid < 192) {
        int row = tid / 3, part = tid - row * 3;
        ((uint4*)(yb + (size_t)(n0 + row) * 32))[part] = ((const uint4*)(sO + row * 32))[part];
    }
}

// ---------------- final: relu(bn) -> emb + segment_max ----------------
__global__ __launch_bounds__(256) void final_kernel(const float* __restrict__ a, const float* __restrict__ ss,
                                                    const int* __restrict__ batch, float* __restrict__ emb,
                                                    unsigned int* __restrict__ ge) {
    __shared__ unsigned int lmax[8 * DIM];
    __shared__ float sS[2 * DIM];
    __shared__ int sg[2];
    int tid = threadIdx.x;
    if (tid < 2 * DIM) sS[tid] = ss[tid];
    int n0 = blockIdx.x * 256;
    if (tid == 0) {
        int nlast = min(n0 + 255, NN - 1);
        sg[0] = batch[n0];
        sg[1] = batch[nlast] - batch[n0] + 1;
    }
    for (int i = tid; i < 8 * DIM; i += 256) lmax[i] = 0u;
    __syncthreads();
    int gmin = sg[0], gspan = sg[1];
    bool uselds = (gspan <= 8);
    int n = n0 + tid;
    if (n < NN) {
        int g = batch[n];
        float vals[DIM];
        const float4* ar = (const float4*)(a + (size_t)n * DIM);
        float4* er = (float4*)(emb + (size_t)n * DIM);
        #pragma unroll
        for (int c = 0; c < 5; ++c) {
            float4 v = ar[c];
            float r0 = fmaxf(v.x * sS[4*c+0] + sS[DIM + 4*c+0], 0.0f);
            float r1 = fmaxf(v.y * sS[4*c+1] + sS[DIM + 4*c+1], 0.0f);
            float r2 = fmaxf(v.z * sS[4*c+2] + sS[DIM + 4*c+2], 0.0f);
            float r3 = fmaxf(v.w * sS[4*c+3] + sS[DIM + 4*c+3], 0.0f);
            er[c] = make_float4(r0, r1, r2, r3);
            vals[4*c+0] = r0; vals[4*c+1] = r1; vals[4*c+2] = r2; vals[4*c+3] = r3;
        }
        if (uselds) {
            int base = (g - gmin) * DIM;
            #pragma unroll
            for (int jo = 0; jo < DIM; ++jo) {
                int j = (jo + tid) % DIM;
                atomicMax(&lmax[base + j], __float_as_uint(vals[j]));
            }
        } else {
            #pragma unroll
            for (int jo = 0; jo < DIM; ++jo) {
                int j = (jo + tid) % DIM;
                atomicMax(&ge[g * DIM + j], __float_as_uint(vals[j]));
            }
        }
    }
    __syncthreads();
    if (uselds) {
        for (int i = tid; i < gspan * DIM; i += 256) {
            unsigned int v = lmax[i];
            if (v) atomicMax(&ge[gmin * DIM + i], v);
        }
    }
}

// ---------------- fc head ----------------
__global__ __launch_bounds__(256) void fc_kernel(const float* __restrict__ ge, const float* __restrict__ fcW,
                                                 const float* __restrict__ fcb, float* __restrict__ out) {
    int gid = blockIdx.x * 256 + threadIdx.x;
    if (gid >= NGR * NCL) return;
    int g = gid >> 1, c = gid & 1;
    float acc = fcb[c];
    #pragma unroll
    for (int d = 0; d < DIM; ++d) acc += ge[g * DIM + d] * fcW[d * NCL + c];
    out[gid] = acc;
}

extern "C" void kernel_launch(void* const* d_in, const int* in_sizes, int n_in,
                              void* d_out, int out_size, void* d_ws, size_t ws_size,
                              hipStream_t stream) {
    const float* x     = (const float*)d_in[0];
    const int*   ei    = (const int*)d_in[1];
    const int*   src   = ei;
    const int*   dst   = ei + NE;
    const int*   batch = (const int*)d_in[2];
    const float* W0 = (const float*)d_in[3];  const float* b0 = (const float*)d_in[4];
    const float* g0 = (const float*)d_in[5];  const float* be0 = (const float*)d_in[6];
    const float* W1 = (const float*)d_in[7];  const float* b1 = (const float*)d_in[8];
    const float* g1 = (const float*)d_in[9];  const float* be1 = (const float*)d_in[10];
    const float* W2 = (const float*)d_in[11]; const float* b2 = (const float*)d_in[12];
    const float* g2 = (const float*)d_in[13]; const float* be2 = (const float*)d_in[14];
    const float* fcW = (const float*)d_in[15]; const float* fcb = (const float*)d_in[16];

    float* ws = (float*)d_ws;
    float* dinv     = ws;                               // NN
    int*   rowstart = (int*)(ws + NN);                  // NN
    float* stats    = ws + 2 * NN;                      // 192
    float* ss       = stats + 192;                      // 120
    int*   ghist    = (int*)(ss + 120);                 // NCTR
    int*   bbase    = ghist + NCTR;                     // NCTR+1
    int*   bcur     = bbase + NCTR + 1;                 // NCTR
    float* agg      = ws + 409700;                      // NN*DIM fp32; aliases packed[]
    unsigned int* packed = (unsigned int*)agg;          // NE u32 == NN*DIM
    ushort_t* ybuf  = (ushort_t*)(ws + 4409712);        // NN rows x 64B (40B data + 24B pad)
    int*   col      = (int*)(ws + 4409712 + (size_t)NN * 16);   // NE ints

    float* emb    = (float*)d_out;                      // NN*DIM
    float* ge     = emb + (size_t)NN * DIM;             // NGR*DIM
    float* logits = ge + NGR * DIM;                     // NGR*NCL

    const int N_BLKS = (NN + 255) / 256;                // 782
    const int L_BLKS = NN / 64;                         // 3125 (linears)
    const int G_BLKS = (NN + 127) / 128;                // 1563 (gather)

    hipMemsetAsync(ghist, 0, NCTR * sizeof(int), stream);
    hipMemsetAsync(stats, 0, 192 * sizeof(float), stream);
    hipMemsetAsync(ge, 0, NGR * DIM * sizeof(float), stream);

    // ---- CSR build: two-level multisplit, (dst_low, src_slice)-sorted segments ----
    hist_kernel<<<NT2, 256, 0, stream>>>(dst, ghist);
    scan_small_kernel<<<1, 1024, 0, stream>>>(ghist, bbase, bcur);
    p2_kernel<<<NT2, 256, 0, stream>>>(src, dst, bcur, packed);
    p3_kernel<<<BKT, 256, 0, stream>>>(packed, bbase, col, rowstart, dinv);

    lin0_kernel<<<L_BLKS, 256, 0, stream>>>(x, W0, dinv, ybuf);   // packed dead after p3

    gather_kernel<<<G_BLKS, 256, 0, stream>>>(ybuf, col, rowstart, dinv, b0, agg, stats);
    bn_param_kernel<<<1, 32, 0, stream>>>(stats, g0, be0, ss);
    lin_next_kernel<<<L_BLKS, 256, 0, stream>>>(agg, ss, W1, dinv, ybuf);

    gather_kernel<<<G_BLKS, 256, 0, stream>>>(ybuf, col, rowstart, dinv, b1, agg, stats + 64);
    bn_param_kernel<<<1, 32, 0, stream>>>(stats + 64, g1, be1, ss + 40);
    lin_next_kernel<<<L_BLKS, 256, 0, stream>>>(agg, ss + 40, W2, dinv, ybuf);

    gather_kernel<<<G_BLKS, 256, 0, stream>>>(ybuf, col, rowstart, dinv, b2, agg, stats + 128);
    bn_param_kernel<<<1, 32, 0, stream>>>(stats + 128, g2, be2, ss + 80);

    final_kernel<<<N_BLKS, 256, 0, stream>>>(agg, ss + 80, batch, emb, (unsigned int*)ge);
    fc_kernel<<<(NGR * NCL + 255) / 256, 256, 0, stream>>>(ge, fcW, fcb, logits);
}